// Round 4
// baseline (378.452 us; speedup 1.0000x reference)
//
#include <hip/hip_runtime.h>
#include <stdint.h>

typedef unsigned short u16;
typedef unsigned int u32;
typedef _Float16 half8 __attribute__((ext_vector_type(8)));
typedef _Float16 half4 __attribute__((ext_vector_type(4)));
typedef float floatx4 __attribute__((ext_vector_type(4)));

__device__ __forceinline__ void splitf(float a, u16* hi, u16* lo) {
  union { _Float16 h; u16 u; } ch, cl;
  ch.h = (_Float16)a;
  cl.h = (_Float16)(a - (float)ch.h);
  *hi = ch.u; *lo = cl.u;
}

// ---------------- merged prep kernel ----------------
// grid 2752 blocks x 256:
//   [0,2048)     gn_partial  (GroupNorm partial sums; 8 float4/thread in flight)
//   [2048,2240)  ln_kv       (LayerNorm(context) + K/V projections, split fp16)
//   [2240,2752)  prep_w      (transpose Wq/Wo into split fp16 planes [n][k])
// gsum[g] at stats[g*16], gsq[g] at stats[256+g*16] (one cache line per counter).
__global__ void prep_all(const float* __restrict__ x, float* __restrict__ stats,
                         const float* __restrict__ ctx, const float* __restrict__ lng,
                         const float* __restrict__ lnb, const float* __restrict__ Wk,
                         const float* __restrict__ Wv,
                         u16* __restrict__ kh, u16* __restrict__ kl,
                         u16* __restrict__ vh, u16* __restrict__ vl,
                         const float* __restrict__ wq, const float* __restrict__ wo,
                         u16* __restrict__ wqt_hi, u16* __restrict__ wqt_lo,
                         u16* __restrict__ wot_hi, u16* __restrict__ wot_lo) {
  __shared__ float smem[776];  // ln: lnv[768]+red[8]; gn: red[8]; pw: tile[16][17]
  int bid = blockIdx.x;
  int t = threadIdx.x;

  if (bid < 2048) {
    // ---- gn_partial: bg = bid>>7 (16 groups x 128 chunks of 8192 floats) ----
    int bg = bid >> 7;
    int chunk = bid & 127;
    size_t base = ((size_t)bg << 20) + ((size_t)chunk << 13);
    float4 v[8];
#pragma unroll
    for (int it = 0; it < 8; ++it)
      v[it] = *(const float4*)(x + base + (size_t)it * 1024 + t * 4);
    float s = 0.f, sq = 0.f;
#pragma unroll
    for (int it = 0; it < 8; ++it) {
      s += v[it].x + v[it].y + v[it].z + v[it].w;
      sq += v[it].x * v[it].x + v[it].y * v[it].y + v[it].z * v[it].z + v[it].w * v[it].w;
    }
    for (int d = 32; d; d >>= 1) { s += __shfl_xor(s, d, 64); sq += __shfl_xor(sq, d, 64); }
    float* red = smem;
    int wv = t >> 6, lane = t & 63;
    if (lane == 0) { red[wv] = s; red[4 + wv] = sq; }
    __syncthreads();
    if (t == 0) {
      atomicAdd(&stats[bg * 16], red[0] + red[1] + red[2] + red[3]);
      atomicAdd(&stats[256 + bg * 16], red[4] + red[5] + red[6] + red[7]);
    }
    return;
  }

  if (bid < 2240) {
    // ---- ln_kv ----
    int kb = bid - 2048;
    int key = kb % 96;
    int b = kb / 96;
    size_t ko = (size_t)(b * 96 + key) * 256 + t;
    size_t vo = ((size_t)(b * 8 + (t >> 5)) * 32 + (t & 31)) * 96 + key;
    if (key >= 77) {
      kh[ko] = 0; kl[ko] = 0; vh[vo] = 0; vl[vo] = 0;
      return;
    }
    float* lnv = smem;
    float* red = smem + 768;
    const float* row = ctx + (size_t)(b * 77 + key) * 768;
    float v0 = row[t], v1 = row[t + 256], v2 = row[t + 512];
    float s = v0 + v1 + v2, sq = v0 * v0 + v1 * v1 + v2 * v2;
    for (int d = 32; d; d >>= 1) { s += __shfl_xor(s, d, 64); sq += __shfl_xor(sq, d, 64); }
    int wv = t >> 6, lane = t & 63;
    if (!lane) { red[wv] = s; red[4 + wv] = sq; }
    __syncthreads();
    float S = red[0] + red[1] + red[2] + red[3];
    float SQ = red[4] + red[5] + red[6] + red[7];
    const float invD = 1.0f / 768.0f;
    float mean = S * invD;
    float rstd = rsqrtf(SQ * invD - mean * mean + 1e-5f);
    lnv[t]       = (v0 - mean) * rstd * lng[t]       + lnb[t];
    lnv[t + 256] = (v1 - mean) * rstd * lng[t + 256] + lnb[t + 256];
    lnv[t + 512] = (v2 - mean) * rstd * lng[t + 512] + lnb[t + 512];
    __syncthreads();
    float a0 = 0.f, a1 = 0.f, a2 = 0.f, a3 = 0.f;
    float c0 = 0.f, c1 = 0.f, c2 = 0.f, c3 = 0.f;
    for (int e = 0; e < 768; e += 4) {
      float w0 = lnv[e], w1 = lnv[e + 1], w2 = lnv[e + 2], w3 = lnv[e + 3];
      a0 += w0 * Wk[(e) * 256 + t];     a1 += w1 * Wk[(e + 1) * 256 + t];
      a2 += w2 * Wk[(e + 2) * 256 + t]; a3 += w3 * Wk[(e + 3) * 256 + t];
      c0 += w0 * Wv[(e) * 256 + t];     c1 += w1 * Wv[(e + 1) * 256 + t];
      c2 += w2 * Wv[(e + 2) * 256 + t]; c3 += w3 * Wv[(e + 3) * 256 + t];
    }
    float ak = (a0 + a1) + (a2 + a3);
    float av = (c0 + c1) + (c2 + c3);
    splitf(ak, &kh[ko], &kl[ko]);
    splitf(av, &vh[vo], &vl[vo]);
    return;
  }

  // ---- prep_w ----
  {
    int pb = bid - 2240;
    int bx = pb & 15, by = (pb >> 4) & 15, bz = pb >> 8;
    float (*tile)[17] = (float(*)[17])smem;
    const float* src = bz ? wo : wq;
    u16* dhi = bz ? wot_hi : wqt_hi;
    u16* dlo = bz ? wot_lo : wqt_lo;
    int r0 = by * 16, c0 = bx * 16;
    int r = t >> 4, c = t & 15;
    tile[r][c] = src[(r0 + r) * 256 + c0 + c];
    __syncthreads();
    float a = tile[c][r];
    int o = (c0 + r) * 256 + r0 + c;
    splitf(a, &dhi[o], &dlo[o]);
  }
}

// ---------------- fused Q-proj + attention + out-proj ----------------
// grid 2048: b = blk>>10, s0 = (blk&1023)*32. 256 threads = 4 waves.
// Round-4 restructure: QK^T computed SWAPPED (A=K, B=Q^T) so each lane holds
// S^T[key=kt*16+quad*4+r][q=ml] — which is exactly the B-fragment layout of
// mfma_f32_16x16x16_f16. P therefore stays in registers (no LDS round-trip),
// PV = mfma16(V^T_frag, p_frag) with V^T frags being the existing vtw layout.
// Deletes the P LDS buffer -> 33792B LDS -> 4 blocks/CU (launch_bounds(256,4)).
#define QSTR 264   // qs row stride (u16): 16B-aligned rows, +4 bank shift/row
__global__ __launch_bounds__(256, 4) void fused_qao(
    const float* __restrict__ x,
    const u16* __restrict__ wqt_hi, const u16* __restrict__ wqt_lo,
    const u16* __restrict__ wot_hi, const u16* __restrict__ wot_lo,
    const u16* __restrict__ kws_hi, const u16* __restrict__ kws_lo,
    const u16* __restrict__ vtw_hi, const u16* __restrict__ vtw_lo,
    const float* __restrict__ gng, const float* __restrict__ gnb,
    const float* __restrict__ stats,
    const float* __restrict__ bo, float* __restrict__ out) {
  __shared__ u16 qhi[32 * QSTR];  // GN(x)^T tile during Step A; then Q; then attn_out
  __shared__ u16 qlo[32 * QSTR];
  int t = threadIdx.x, lane = t & 63, wv = t >> 6;
  int ml = lane & 15, quad = lane >> 4;
  int b = blockIdx.x >> 10;
  int s0 = (blockIdx.x & 1023) * 32;

  // ---- Issue Step A's first B-fragments NOW; they land during GN staging.
  half8 nbh[4], nbl[4];
#pragma unroll
  for (int j = 0; j < 4; ++j) {
    size_t wo_ = (size_t)(wv * 64 + j * 16 + ml) * 256 + quad * 8;
    nbh[j] = *(const half8*)(wqt_hi + wo_);
    nbl[j] = *(const half8*)(wqt_lo + wo_);
  }
  __builtin_amdgcn_sched_barrier(0);

  // ---- Stage GN(x)^T tile [32 s][256 c] into qs (hi/lo), finalize GN inline.
  {
    const float invN = 1.0f / 1048576.0f;
    int sc_ = (t & 7) * 4;  // s-chunk start
    float4 xv[8];
#pragma unroll
    for (int p = 0; p < 8; ++p) {
      int c = p * 32 + (t >> 3);
      xv[p] = *(const float4*)(x + (((size_t)(b * 256 + c)) << 15) + s0 + sc_);
    }
#pragma unroll
    for (int p = 0; p < 8; ++p) {
      int c = p * 32 + (t >> 3);
      int bg = b * 8 + (c >> 5);
      float mean = stats[bg * 16] * invN;
      float var = stats[256 + bg * 16] * invN - mean * mean;
      float rstd = rsqrtf(var + 1e-5f);
      float scale = rstd * gng[c];
      float shift = gnb[c] - mean * scale;
      float xa[4] = {xv[p].x, xv[p].y, xv[p].z, xv[p].w};
#pragma unroll
      for (int e = 0; e < 4; ++e) {
        int o = (sc_ + e) * QSTR + c;
        splitf(xa[e] * scale + shift, &qhi[o], &qlo[o]);
      }
    }
  }
  __syncthreads();

  // ---- Step A: Q[32][256] = A-tile @ Wq^T. No barriers in k-loop.
  floatx4 acc[2][4];
#pragma unroll
  for (int i = 0; i < 2; ++i)
#pragma unroll
    for (int j = 0; j < 4; ++j) acc[i][j] = (floatx4){0.f, 0.f, 0.f, 0.f};
#pragma unroll
  for (int k0 = 0; k0 < 256; k0 += 32) {
    half8 ah[2], al[2], bh[4], bl[4];
#pragma unroll
    for (int j = 0; j < 4; ++j) { bh[j] = nbh[j]; bl[j] = nbl[j]; }
    if (k0 < 224) {
#pragma unroll
      for (int j = 0; j < 4; ++j) {
        size_t wo_ = (size_t)(wv * 64 + j * 16 + ml) * 256 + k0 + 32 + quad * 8;
        nbh[j] = *(const half8*)(wqt_hi + wo_);
        nbl[j] = *(const half8*)(wqt_lo + wo_);
      }
    }
#pragma unroll
    for (int i = 0; i < 2; ++i) {
      ah[i] = *(const half8*)&qhi[(i * 16 + ml) * QSTR + k0 + quad * 8];
      al[i] = *(const half8*)&qlo[(i * 16 + ml) * QSTR + k0 + quad * 8];
    }
    __builtin_amdgcn_sched_barrier(0);  // pin next-k loads above the MFMA cluster
#pragma unroll
    for (int i = 0; i < 2; ++i)
#pragma unroll
      for (int j = 0; j < 4; ++j) {
        acc[i][j] = __builtin_amdgcn_mfma_f32_16x16x32_f16(al[i], bh[j], acc[i][j], 0, 0, 0);
        acc[i][j] = __builtin_amdgcn_mfma_f32_16x16x32_f16(ah[i], bl[j], acc[i][j], 0, 0, 0);
        acc[i][j] = __builtin_amdgcn_mfma_f32_16x16x32_f16(ah[i], bh[j], acc[i][j], 0, 0, 0);
      }
  }
  __syncthreads();  // all waves done reading A-tile before overwriting with Q
#pragma unroll
  for (int i = 0; i < 2; ++i)
#pragma unroll
    for (int j = 0; j < 4; ++j)
#pragma unroll
      for (int r = 0; r < 4; ++r) {
        int o = (i * 16 + quad * 4 + r) * QSTR + wv * 64 + j * 16 + ml;
        splitf(acc[i][j][r], &qhi[o], &qlo[o]);
      }
  // ---- Preload K fragments for this wave's FIRST head; land during barrier.
  int h0 = (wv >> 1) * 4;
  half8 kbh[5], kbl[5];
#pragma unroll
  for (int kt = 0; kt < 5; ++kt) {
    size_t ko = (size_t)(b * 96 + kt * 16 + ml) * 256 + h0 * 32 + quad * 8;
    kbh[kt] = *(const half8*)(kws_hi + ko);
    kbl[kt] = *(const half8*)(kws_lo + ko);
  }
  __builtin_amdgcn_sched_barrier(0);
  __syncthreads();  // Q complete (cross-wave columns)

  // ---- Step B: attention, fully in-register P.
  // wave -> rows (wv&1)*16.., heads (wv>>1)*4... Lane (ml,quad) roles:
  //   S^T MFMA out: key = kt*16 + quad*4 + r, q = r16 + ml
  //   -> same layout as mfma_f32_16x16x16_f16 B-fragment (col=ml, k=quad*4+e)
  int r16 = (wv & 1) * 16;
  const float scl = 0.17677669529663687f;
  const floatx4 z = {0.f, 0.f, 0.f, 0.f};
#pragma unroll
  for (int hh = 0; hh < 4; ++hh) {
    int h = h0 + hh;
    half8 qfh = *(const half8*)&qhi[(r16 + ml) * QSTR + h * 32 + quad * 8];
    half8 qfl = *(const half8*)&qlo[(r16 + ml) * QSTR + h * 32 + quad * 8];
    // Issue ALL V^T fragments for this head now; consumed after softmax.
    // vtw layout [b][h][d][key]: row = db*16+ml, keys kt*16+quad*4.. (half4).
    half4 vfh[2][5], vfl[2][5];
#pragma unroll
    for (int db = 0; db < 2; ++db)
#pragma unroll
      for (int kt = 0; kt < 5; ++kt) {
        size_t vo = (size_t)((b * 8 + h) * 32 + db * 16 + ml) * 96 + kt * 16 + quad * 4;
        vfh[db][kt] = *(const half4*)(vtw_hi + vo);
        vfl[db][kt] = *(const half4*)(vtw_lo + vo);
      }
    // S^T = K x Q^T (swapped operands; same products as before, transposed).
    floatx4 sc[5];
    __builtin_amdgcn_s_setprio(1);
#pragma unroll
    for (int kt = 0; kt < 5; ++kt) {
      floatx4 a = __builtin_amdgcn_mfma_f32_16x16x32_f16(kbl[kt], qfh, z, 0, 0, 0);
      a = __builtin_amdgcn_mfma_f32_16x16x32_f16(kbh[kt], qfl, a, 0, 0, 0);
      sc[kt] = __builtin_amdgcn_mfma_f32_16x16x32_f16(kbh[kt], qfh, a, 0, 0, 0);
    }
    __builtin_amdgcn_s_setprio(0);
    // Issue next head's K loads; consumed after softmax+PV.
    if (hh < 3) {
#pragma unroll
      for (int kt = 0; kt < 5; ++kt) {
        size_t ko = (size_t)(b * 96 + kt * 16 + ml) * 256 + (h + 1) * 32 + quad * 8;
        kbh[kt] = *(const half8*)(kws_hi + ko);
        kbl[kt] = *(const half8*)(kws_lo + ko);
      }
    }
    __builtin_amdgcn_sched_barrier(0);
    // softmax over keys (key = kt*16+quad*4+r), per q=ml. Scalar mx/sm per
    // lane + 2 shfl rounds across quads (lanes ^16, ^32).
    float mx = -1e30f;
#pragma unroll
    for (int kt = 0; kt < 5; ++kt) {
      int kbase = kt * 16 + quad * 4;
#pragma unroll
      for (int r = 0; r < 4; ++r) {
        float v = (kbase + r < 77) ? sc[kt][r] * scl : -1e30f;
        sc[kt][r] = v;
        mx = fmaxf(mx, v);
      }
    }
    mx = fmaxf(mx, __shfl_xor(mx, 16, 64));
    mx = fmaxf(mx, __shfl_xor(mx, 32, 64));
    float sm = 0.f;
#pragma unroll
    for (int kt = 0; kt < 5; ++kt)
#pragma unroll
      for (int r = 0; r < 4; ++r) {
        float p = __expf(sc[kt][r] - mx);
        sc[kt][r] = p;
        sm += p;
      }
    sm += __shfl_xor(sm, 16, 64);
    sm += __shfl_xor(sm, 32, 64);
    float inv = 1.0f / sm;
    half4 pb[5];
#pragma unroll
    for (int kt = 0; kt < 5; ++kt) {
      pb[kt][0] = (_Float16)(sc[kt][0] * inv);
      pb[kt][1] = (_Float16)(sc[kt][1] * inv);
      pb[kt][2] = (_Float16)(sc[kt][2] * inv);
      pb[kt][3] = (_Float16)(sc[kt][3] * inv);
    }
    // PV^T: out^T[d][q] accumulated via 16x16x16 MFMAs, P straight from regs.
    floatx4 o0 = z, o1 = z;
    __builtin_amdgcn_s_setprio(1);
#pragma unroll
    for (int kt = 0; kt < 5; ++kt) {
      o0 = __builtin_amdgcn_mfma_f32_16x16x16f16(vfl[0][kt], pb[kt], o0, 0, 0, 0);
      o0 = __builtin_amdgcn_mfma_f32_16x16x16f16(vfh[0][kt], pb[kt], o0, 0, 0, 0);
      o1 = __builtin_amdgcn_mfma_f32_16x16x16f16(vfl[1][kt], pb[kt], o1, 0, 0, 0);
      o1 = __builtin_amdgcn_mfma_f32_16x16x16f16(vfh[1][kt], pb[kt], o1, 0, 0, 0);
    }
    __builtin_amdgcn_s_setprio(0);
    // Lane holds attn_out[q = r16+ml][d = db*16 + quad*4 + r]; write into qs
    // row r16+ml, cols h*32 + d — rows disjoint across waves (r16), cols by h.
#pragma unroll
    for (int r = 0; r < 4; ++r) {
      int o0i = (r16 + ml) * QSTR + h * 32 + quad * 4 + r;
      splitf(o0[r], &qhi[o0i], &qlo[o0i]);
      int o1i = o0i + 16;
      splitf(o1[r], &qhi[o1i], &qlo[o1i]);
    }
  }
  // ---- Issue Step C's first B-fragments; they land during the barrier.
#pragma unroll
  for (int j = 0; j < 4; ++j) {
    size_t wo_ = (size_t)(wv * 64 + j * 16 + ml) * 256 + quad * 8;
    nbh[j] = *(const half8*)(wot_hi + wo_);
    nbl[j] = *(const half8*)(wot_lo + wo_);
  }
  __builtin_amdgcn_sched_barrier(0);
  __syncthreads();  // attn_out complete before Step C reads all columns

  // ---- Step C: out = attn_out @ Wo^T + bo + x. No barriers in k-loop.
#pragma unroll
  for (int i = 0; i < 2; ++i)
#pragma unroll
    for (int j = 0; j < 4; ++j) acc[i][j] = (floatx4){0.f, 0.f, 0.f, 0.f};
#pragma unroll
  for (int k0 = 0; k0 < 256; k0 += 32) {
    half8 ah[2], al[2], bh[4], bl[4];
#pragma unroll
    for (int j = 0; j < 4; ++j) { bh[j] = nbh[j]; bl[j] = nbl[j]; }
    if (k0 < 224) {
#pragma unroll
      for (int j = 0; j < 4; ++j) {
        size_t wo_ = (size_t)(wv * 64 + j * 16 + ml) * 256 + k0 + 32 + quad * 8;
        nbh[j] = *(const half8*)(wot_hi + wo_);
        nbl[j] = *(const half8*)(wot_lo + wo_);
      }
    }
#pragma unroll
    for (int i = 0; i < 2; ++i) {
      ah[i] = *(const half8*)&qhi[(i * 16 + ml) * QSTR + k0 + quad * 8];
      al[i] = *(const half8*)&qlo[(i * 16 + ml) * QSTR + k0 + quad * 8];
    }
    __builtin_amdgcn_sched_barrier(0);  // pin next-k loads above the MFMA cluster
#pragma unroll
    for (int i = 0; i < 2; ++i)
#pragma unroll
      for (int j = 0; j < 4; ++j) {
        acc[i][j] = __builtin_amdgcn_mfma_f32_16x16x32_f16(al[i], bh[j], acc[i][j], 0, 0, 0);
        acc[i][j] = __builtin_amdgcn_mfma_f32_16x16x32_f16(ah[i], bl[j], acc[i][j], 0, 0, 0);
        acc[i][j] = __builtin_amdgcn_mfma_f32_16x16x32_f16(ah[i], bh[j], acc[i][j], 0, 0, 0);
      }
  }
#pragma unroll
  for (int i = 0; i < 2; ++i) {
    int sp = s0 + i * 16 + quad * 4;
#pragma unroll
    for (int j = 0; j < 4; ++j) {
      int col = wv * 64 + j * 16 + ml;
      float bias = bo[col];
      size_t o = (((size_t)(b * 256 + col)) << 15) + sp;
      float4 xv = *(const float4*)(x + o);
      float4 ov;
      ov.x = acc[i][j][0] + bias + xv.x;
      ov.y = acc[i][j][1] + bias + xv.y;
      ov.z = acc[i][j][2] + bias + xv.z;
      ov.w = acc[i][j][3] + bias + xv.w;
      *(float4*)(out + o) = ov;
    }
  }
}

extern "C" void kernel_launch(void* const* d_in, const int* in_sizes, int n_in,
                              void* d_out, int out_size, void* d_ws, size_t ws_size,
                              hipStream_t stream) {
  (void)out_size; (void)ws_size;
  int idx[11] = {0, 1, 2, 3, 4, 5, 6, 7, 8, 9, 10};  // x,ctx,gng,gnb,lng,lnb,Wq,Wk,Wv,Wo,bo
  static const int dsz[11] = {16777216, 118272, 256, 256, 768, 768,
                              65536, 196608, 196608, 65536, 256};
  bool dict = (n_in == 11);
  if (dict)
    for (int i = 0; i < 11; ++i)
      if (in_sizes[i] != dsz[i]) { dict = false; break; }
  if (!dict && n_in == 11) {
    static const int ssz[11] = {196608, 65536, 65536, 196608, 256, 118272,
                                256, 256, 768, 768, 16777216};
    bool srt = true;
    for (int i = 0; i < 11; ++i)
      if (in_sizes[i] != ssz[i]) { srt = false; break; }
    if (srt) {
      idx[0] = 10; idx[1] = 5; idx[2] = 7; idx[3] = 6; idx[4] = 9; idx[5] = 8;
      idx[6] = 2;  idx[7] = 0; idx[8] = 3; idx[9] = 1; idx[10] = 4;
    }
  }
  const float* x   = (const float*)d_in[idx[0]];
  const float* ctx = (const float*)d_in[idx[1]];
  const float* gng = (const float*)d_in[idx[2]];
  const float* gnb = (const float*)d_in[idx[3]];
  const float* lng = (const float*)d_in[idx[4]];
  const float* lnb = (const float*)d_in[idx[5]];
  const float* Wq  = (const float*)d_in[idx[6]];
  const float* Wk  = (const float*)d_in[idx[7]];
  const float* Wv  = (const float*)d_in[idx[8]];
  const float* Wo  = (const float*)d_in[idx[9]];
  const float* bo  = (const float*)d_in[idx[10]];
  float* out = (float*)d_out;

  u16* ws = (u16*)d_ws;
  float* stats = (float*)ws;  // 512 floats: gsum[g] at g*16, gsq[g] at 256+g*16
  u16* wqt_hi = ws + 1024;
  u16* wqt_lo = wqt_hi + 65536;
  u16* wot_hi = wqt_lo + 65536;
  u16* wot_lo = wot_hi + 65536;
  u16* kws_hi = wot_lo + 65536;
  u16* kws_lo = kws_hi + 49152;
  u16* vtw_hi = kws_lo + 49152;
  u16* vtw_lo = vtw_hi + 49152;

  hipMemsetAsync(stats, 0, 512 * sizeof(float), stream);
  prep_all<<<2752, 256, 0, stream>>>(x, stats, ctx, lng, lnb, Wk, Wv,
                                     kws_hi, kws_lo, vtw_hi, vtw_lo,
                                     Wq, Wo, wqt_hi, wqt_lo, wot_hi, wot_lo);
  fused_qao<<<2048, 256, 0, stream>>>(x, wqt_hi, wqt_lo, wot_hi, wot_lo,
                                      kws_hi, kws_lo, vtw_hi, vtw_lo,
                                      gng, gnb, stats, bo, out);
}

// Round 5
// 344.442 us; speedup vs baseline: 1.0987x; 1.0987x over previous
//
#include <hip/hip_runtime.h>
#include <stdint.h>

typedef unsigned short u16;
typedef unsigned int u32;
typedef _Float16 half8 __attribute__((ext_vector_type(8)));
typedef _Float16 half4 __attribute__((ext_vector_type(4)));
typedef float floatx4 __attribute__((ext_vector_type(4)));

__device__ __forceinline__ void splitf(float a, u16* hi, u16* lo) {
  union { _Float16 h; u16 u; } ch, cl;
  ch.h = (_Float16)a;
  cl.h = (_Float16)(a - (float)ch.h);
  *hi = ch.u; *lo = cl.u;
}

// ---------------- merged prep kernel ----------------
// grid 2752 blocks x 256:
//   [0,2048)     gn_partial  (GroupNorm partial sums; 8 float4/thread in flight)
//   [2048,2240)  ln_kv       (LayerNorm(context) + K/V projections, split fp16)
//   [2240,2752)  prep_w      (transpose Wq/Wo into split fp16 planes [n][k])
// gsum[g] at stats[g*16], gsq[g] at stats[256+g*16] (one cache line per counter).
__global__ void prep_all(const float* __restrict__ x, float* __restrict__ stats,
                         const float* __restrict__ ctx, const float* __restrict__ lng,
                         const float* __restrict__ lnb, const float* __restrict__ Wk,
                         const float* __restrict__ Wv,
                         u16* __restrict__ kh, u16* __restrict__ kl,
                         u16* __restrict__ vh, u16* __restrict__ vl,
                         const float* __restrict__ wq, const float* __restrict__ wo,
                         u16* __restrict__ wqt_hi, u16* __restrict__ wqt_lo,
                         u16* __restrict__ wot_hi, u16* __restrict__ wot_lo) {
  __shared__ float smem[776];  // ln: lnv[768]+red[8]; gn: red[8]; pw: tile[16][17]
  int bid = blockIdx.x;
  int t = threadIdx.x;

  if (bid < 2048) {
    // ---- gn_partial: bg = bid>>7 (16 groups x 128 chunks of 8192 floats) ----
    int bg = bid >> 7;
    int chunk = bid & 127;
    size_t base = ((size_t)bg << 20) + ((size_t)chunk << 13);
    float4 v[8];
#pragma unroll
    for (int it = 0; it < 8; ++it)
      v[it] = *(const float4*)(x + base + (size_t)it * 1024 + t * 4);
    float s = 0.f, sq = 0.f;
#pragma unroll
    for (int it = 0; it < 8; ++it) {
      s += v[it].x + v[it].y + v[it].z + v[it].w;
      sq += v[it].x * v[it].x + v[it].y * v[it].y + v[it].z * v[it].z + v[it].w * v[it].w;
    }
    for (int d = 32; d; d >>= 1) { s += __shfl_xor(s, d, 64); sq += __shfl_xor(sq, d, 64); }
    float* red = smem;
    int wv = t >> 6, lane = t & 63;
    if (lane == 0) { red[wv] = s; red[4 + wv] = sq; }
    __syncthreads();
    if (t == 0) {
      atomicAdd(&stats[bg * 16], red[0] + red[1] + red[2] + red[3]);
      atomicAdd(&stats[256 + bg * 16], red[4] + red[5] + red[6] + red[7]);
    }
    return;
  }

  if (bid < 2240) {
    // ---- ln_kv ----
    int kb = bid - 2048;
    int key = kb % 96;
    int b = kb / 96;
    size_t ko = (size_t)(b * 96 + key) * 256 + t;
    size_t vo = ((size_t)(b * 8 + (t >> 5)) * 32 + (t & 31)) * 96 + key;
    if (key >= 77) {
      kh[ko] = 0; kl[ko] = 0; vh[vo] = 0; vl[vo] = 0;
      return;
    }
    float* lnv = smem;
    float* red = smem + 768;
    const float* row = ctx + (size_t)(b * 77 + key) * 768;
    float v0 = row[t], v1 = row[t + 256], v2 = row[t + 512];
    float s = v0 + v1 + v2, sq = v0 * v0 + v1 * v1 + v2 * v2;
    for (int d = 32; d; d >>= 1) { s += __shfl_xor(s, d, 64); sq += __shfl_xor(sq, d, 64); }
    int wv = t >> 6, lane = t & 63;
    if (!lane) { red[wv] = s; red[4 + wv] = sq; }
    __syncthreads();
    float S = red[0] + red[1] + red[2] + red[3];
    float SQ = red[4] + red[5] + red[6] + red[7];
    const float invD = 1.0f / 768.0f;
    float mean = S * invD;
    float rstd = rsqrtf(SQ * invD - mean * mean + 1e-5f);
    lnv[t]       = (v0 - mean) * rstd * lng[t]       + lnb[t];
    lnv[t + 256] = (v1 - mean) * rstd * lng[t + 256] + lnb[t + 256];
    lnv[t + 512] = (v2 - mean) * rstd * lng[t + 512] + lnb[t + 512];
    __syncthreads();
    float a0 = 0.f, a1 = 0.f, a2 = 0.f, a3 = 0.f;
    float c0 = 0.f, c1 = 0.f, c2 = 0.f, c3 = 0.f;
    for (int e = 0; e < 768; e += 4) {
      float w0 = lnv[e], w1 = lnv[e + 1], w2 = lnv[e + 2], w3 = lnv[e + 3];
      a0 += w0 * Wk[(e) * 256 + t];     a1 += w1 * Wk[(e + 1) * 256 + t];
      a2 += w2 * Wk[(e + 2) * 256 + t]; a3 += w3 * Wk[(e + 3) * 256 + t];
      c0 += w0 * Wv[(e) * 256 + t];     c1 += w1 * Wv[(e + 1) * 256 + t];
      c2 += w2 * Wv[(e + 2) * 256 + t]; c3 += w3 * Wv[(e + 3) * 256 + t];
    }
    float ak = (a0 + a1) + (a2 + a3);
    float av = (c0 + c1) + (c2 + c3);
    splitf(ak, &kh[ko], &kl[ko]);
    splitf(av, &vh[vo], &vl[vo]);
    return;
  }

  // ---- prep_w ----
  {
    int pb = bid - 2240;
    int bx = pb & 15, by = (pb >> 4) & 15, bz = pb >> 8;
    float (*tile)[17] = (float(*)[17])smem;
    const float* src = bz ? wo : wq;
    u16* dhi = bz ? wot_hi : wqt_hi;
    u16* dlo = bz ? wot_lo : wqt_lo;
    int r0 = by * 16, c0 = bx * 16;
    int r = t >> 4, c = t & 15;
    tile[r][c] = src[(r0 + r) * 256 + c0 + c];
    __syncthreads();
    float a = tile[c][r];
    int o = (c0 + r) * 256 + r0 + c;
    splitf(a, &dhi[o], &dlo[o]);
  }
}

// ---------------- fused Q-proj + attention + out-proj ----------------
// grid 2048: b = blk>>10, s0 = (blk&1023)*32. 256 threads = 4 waves.
// Structure (round 4, kept): swapped QK^T (A=K, B=Q^T) so each lane holds
// S^T[key][q] in the exact B-fragment layout of mfma_f32_16x16x16_f16 -> P
// never touches LDS; PV = mfma16(V^T_frag, p_frag). LDS 33792B -> 4 blocks/CU.
// Round-5 fix: NO sched_barrier pins, NO next-head K prefetch. Round 4 proved
// pinned liveness at the 128-VGPR cap (launch_bounds 256,4) spills to scratch
// (WRITE_SIZE 65->186MB). Latency hiding now comes from 16 waves/CU TLP; the
// compiler schedules loads under the register budget (round 2/3: VGPR 68-84,
// zero spill, same perf as pinned).
#define QSTR 264   // qs row stride (u16): 16B-aligned rows, +4 bank shift/row
__global__ __launch_bounds__(256, 4) void fused_qao(
    const float* __restrict__ x,
    const u16* __restrict__ wqt_hi, const u16* __restrict__ wqt_lo,
    const u16* __restrict__ wot_hi, const u16* __restrict__ wot_lo,
    const u16* __restrict__ kws_hi, const u16* __restrict__ kws_lo,
    const u16* __restrict__ vtw_hi, const u16* __restrict__ vtw_lo,
    const float* __restrict__ gng, const float* __restrict__ gnb,
    const float* __restrict__ stats,
    const float* __restrict__ bo, float* __restrict__ out) {
  __shared__ u16 qhi[32 * QSTR];  // GN(x)^T tile during Step A; then Q; then attn_out
  __shared__ u16 qlo[32 * QSTR];
  int t = threadIdx.x, lane = t & 63, wv = t >> 6;
  int ml = lane & 15, quad = lane >> 4;
  int b = blockIdx.x >> 10;
  int s0 = (blockIdx.x & 1023) * 32;

  // ---- Issue Step A's first B-fragments early; land during GN staging.
  half8 nbh[4], nbl[4];
#pragma unroll
  for (int j = 0; j < 4; ++j) {
    size_t wo_ = (size_t)(wv * 64 + j * 16 + ml) * 256 + quad * 8;
    nbh[j] = *(const half8*)(wqt_hi + wo_);
    nbl[j] = *(const half8*)(wqt_lo + wo_);
  }

  // ---- Stage GN(x)^T tile [32 s][256 c] into qs (hi/lo), finalize GN inline.
  {
    const float invN = 1.0f / 1048576.0f;
    int sc_ = (t & 7) * 4;  // s-chunk start
    float4 xv[8];
#pragma unroll
    for (int p = 0; p < 8; ++p) {
      int c = p * 32 + (t >> 3);
      xv[p] = *(const float4*)(x + (((size_t)(b * 256 + c)) << 15) + s0 + sc_);
    }
#pragma unroll
    for (int p = 0; p < 8; ++p) {
      int c = p * 32 + (t >> 3);
      int bg = b * 8 + (c >> 5);
      float mean = stats[bg * 16] * invN;
      float var = stats[256 + bg * 16] * invN - mean * mean;
      float rstd = rsqrtf(var + 1e-5f);
      float scale = rstd * gng[c];
      float shift = gnb[c] - mean * scale;
      float xa[4] = {xv[p].x, xv[p].y, xv[p].z, xv[p].w};
#pragma unroll
      for (int e = 0; e < 4; ++e) {
        int o = (sc_ + e) * QSTR + c;
        splitf(xa[e] * scale + shift, &qhi[o], &qlo[o]);
      }
    }
  }
  __syncthreads();

  // ---- Step A: Q[32][256] = A-tile @ Wq^T. No barriers in k-loop.
  floatx4 acc[2][4];
#pragma unroll
  for (int i = 0; i < 2; ++i)
#pragma unroll
    for (int j = 0; j < 4; ++j) acc[i][j] = (floatx4){0.f, 0.f, 0.f, 0.f};
#pragma unroll
  for (int k0 = 0; k0 < 256; k0 += 32) {
    half8 ah[2], al[2], bh[4], bl[4];
#pragma unroll
    for (int j = 0; j < 4; ++j) { bh[j] = nbh[j]; bl[j] = nbl[j]; }
    if (k0 < 224) {
#pragma unroll
      for (int j = 0; j < 4; ++j) {
        size_t wo_ = (size_t)(wv * 64 + j * 16 + ml) * 256 + k0 + 32 + quad * 8;
        nbh[j] = *(const half8*)(wqt_hi + wo_);
        nbl[j] = *(const half8*)(wqt_lo + wo_);
      }
    }
#pragma unroll
    for (int i = 0; i < 2; ++i) {
      ah[i] = *(const half8*)&qhi[(i * 16 + ml) * QSTR + k0 + quad * 8];
      al[i] = *(const half8*)&qlo[(i * 16 + ml) * QSTR + k0 + quad * 8];
    }
#pragma unroll
    for (int i = 0; i < 2; ++i)
#pragma unroll
      for (int j = 0; j < 4; ++j) {
        acc[i][j] = __builtin_amdgcn_mfma_f32_16x16x32_f16(al[i], bh[j], acc[i][j], 0, 0, 0);
        acc[i][j] = __builtin_amdgcn_mfma_f32_16x16x32_f16(ah[i], bl[j], acc[i][j], 0, 0, 0);
        acc[i][j] = __builtin_amdgcn_mfma_f32_16x16x32_f16(ah[i], bh[j], acc[i][j], 0, 0, 0);
      }
  }
  __syncthreads();  // all waves done reading A-tile before overwriting with Q
#pragma unroll
  for (int i = 0; i < 2; ++i)
#pragma unroll
    for (int j = 0; j < 4; ++j)
#pragma unroll
      for (int r = 0; r < 4; ++r) {
        int o = (i * 16 + quad * 4 + r) * QSTR + wv * 64 + j * 16 + ml;
        splitf(acc[i][j][r], &qhi[o], &qlo[o]);
      }
  __syncthreads();  // Q complete (cross-wave columns)

  // ---- Step B: attention, fully in-register P.
  // wave -> rows (wv&1)*16.., heads (wv>>1)*4... Per head, issue order:
  // K loads -> QK^T MFMA -> V loads -> softmax (covers V latency) -> PV.
  int h0 = (wv >> 1) * 4;
  int r16 = (wv & 1) * 16;
  const float scl = 0.17677669529663687f;
  const floatx4 z = {0.f, 0.f, 0.f, 0.f};
#pragma unroll
  for (int hh = 0; hh < 4; ++hh) {
    int h = h0 + hh;
    half8 qfh = *(const half8*)&qhi[(r16 + ml) * QSTR + h * 32 + quad * 8];
    half8 qfl = *(const half8*)&qlo[(r16 + ml) * QSTR + h * 32 + quad * 8];
    half8 kbh[5], kbl[5];
#pragma unroll
    for (int kt = 0; kt < 5; ++kt) {
      size_t ko = (size_t)(b * 96 + kt * 16 + ml) * 256 + h * 32 + quad * 8;
      kbh[kt] = *(const half8*)(kws_hi + ko);
      kbl[kt] = *(const half8*)(kws_lo + ko);
    }
    // S^T = K x Q^T (swapped operands): lane holds S^T[key=kt*16+quad*4+r][q=ml]
    floatx4 sc[5];
    __builtin_amdgcn_s_setprio(1);
#pragma unroll
    for (int kt = 0; kt < 5; ++kt) {
      floatx4 a = __builtin_amdgcn_mfma_f32_16x16x32_f16(kbl[kt], qfh, z, 0, 0, 0);
      a = __builtin_amdgcn_mfma_f32_16x16x32_f16(kbh[kt], qfl, a, 0, 0, 0);
      sc[kt] = __builtin_amdgcn_mfma_f32_16x16x32_f16(kbh[kt], qfh, a, 0, 0, 0);
    }
    __builtin_amdgcn_s_setprio(0);
    // V^T fragments (vtw layout [b][h][d][key]): issued before softmax so the
    // exp/shuffle VALU stretch covers their L2 latency. K regs are dead now.
    half4 vfh[2][5], vfl[2][5];
#pragma unroll
    for (int db = 0; db < 2; ++db)
#pragma unroll
      for (int kt = 0; kt < 5; ++kt) {
        size_t vo = (size_t)((b * 8 + h) * 32 + db * 16 + ml) * 96 + kt * 16 + quad * 4;
        vfh[db][kt] = *(const half4*)(vtw_hi + vo);
        vfl[db][kt] = *(const half4*)(vtw_lo + vo);
      }
    // softmax over keys (key = kt*16+quad*4+r), per q=ml: scalar accumulate
    // + 2 shfl rounds across quads (lanes ^16, ^32).
    float mx = -1e30f;
#pragma unroll
    for (int kt = 0; kt < 5; ++kt) {
      int kbase = kt * 16 + quad * 4;
#pragma unroll
      for (int r = 0; r < 4; ++r) {
        float v = (kbase + r < 77) ? sc[kt][r] * scl : -1e30f;
        sc[kt][r] = v;
        mx = fmaxf(mx, v);
      }
    }
    mx = fmaxf(mx, __shfl_xor(mx, 16, 64));
    mx = fmaxf(mx, __shfl_xor(mx, 32, 64));
    float sm = 0.f;
#pragma unroll
    for (int kt = 0; kt < 5; ++kt)
#pragma unroll
      for (int r = 0; r < 4; ++r) {
        float p = __expf(sc[kt][r] - mx);
        sc[kt][r] = p;
        sm += p;
      }
    sm += __shfl_xor(sm, 16, 64);
    sm += __shfl_xor(sm, 32, 64);
    float inv = 1.0f / sm;
    half4 pb[5];
#pragma unroll
    for (int kt = 0; kt < 5; ++kt) {
      pb[kt][0] = (_Float16)(sc[kt][0] * inv);
      pb[kt][1] = (_Float16)(sc[kt][1] * inv);
      pb[kt][2] = (_Float16)(sc[kt][2] * inv);
      pb[kt][3] = (_Float16)(sc[kt][3] * inv);
    }
    // PV^T: out^T[d][q] via 16x16x16 MFMAs, P straight from registers.
    floatx4 o0 = z, o1 = z;
    __builtin_amdgcn_s_setprio(1);
#pragma unroll
    for (int kt = 0; kt < 5; ++kt) {
      o0 = __builtin_amdgcn_mfma_f32_16x16x16f16(vfl[0][kt], pb[kt], o0, 0, 0, 0);
      o0 = __builtin_amdgcn_mfma_f32_16x16x16f16(vfh[0][kt], pb[kt], o0, 0, 0, 0);
      o1 = __builtin_amdgcn_mfma_f32_16x16x16f16(vfl[1][kt], pb[kt], o1, 0, 0, 0);
      o1 = __builtin_amdgcn_mfma_f32_16x16x16f16(vfh[1][kt], pb[kt], o1, 0, 0, 0);
    }
    __builtin_amdgcn_s_setprio(0);
    // Lane holds attn_out[q = r16+ml][d = db*16 + quad*4 + r]; write into qs
    // row r16+ml, cols h*32 + d — rows disjoint across waves (r16), cols by h.
#pragma unroll
    for (int r = 0; r < 4; ++r) {
      int o0i = (r16 + ml) * QSTR + h * 32 + quad * 4 + r;
      splitf(o0[r], &qhi[o0i], &qlo[o0i]);
      int o1i = o0i + 16;
      splitf(o1[r], &qhi[o1i], &qlo[o1i]);
    }
  }
  // ---- Issue Step C's first B-fragments; they land during the barrier.
#pragma unroll
  for (int j = 0; j < 4; ++j) {
    size_t wo_ = (size_t)(wv * 64 + j * 16 + ml) * 256 + quad * 8;
    nbh[j] = *(const half8*)(wot_hi + wo_);
    nbl[j] = *(const half8*)(wot_lo + wo_);
  }
  __syncthreads();  // attn_out complete before Step C reads all columns

  // ---- Step C: out = attn_out @ Wo^T + bo + x. No barriers in k-loop.
#pragma unroll
  for (int i = 0; i < 2; ++i)
#pragma unroll
    for (int j = 0; j < 4; ++j) acc[i][j] = (floatx4){0.f, 0.f, 0.f, 0.f};
#pragma unroll
  for (int k0 = 0; k0 < 256; k0 += 32) {
    half8 ah[2], al[2], bh[4], bl[4];
#pragma unroll
    for (int j = 0; j < 4; ++j) { bh[j] = nbh[j]; bl[j] = nbl[j]; }
    if (k0 < 224) {
#pragma unroll
      for (int j = 0; j < 4; ++j) {
        size_t wo_ = (size_t)(wv * 64 + j * 16 + ml) * 256 + k0 + 32 + quad * 8;
        nbh[j] = *(const half8*)(wot_hi + wo_);
        nbl[j] = *(const half8*)(wot_lo + wo_);
      }
    }
#pragma unroll
    for (int i = 0; i < 2; ++i) {
      ah[i] = *(const half8*)&qhi[(i * 16 + ml) * QSTR + k0 + quad * 8];
      al[i] = *(const half8*)&qlo[(i * 16 + ml) * QSTR + k0 + quad * 8];
    }
#pragma unroll
    for (int i = 0; i < 2; ++i)
#pragma unroll
      for (int j = 0; j < 4; ++j) {
        acc[i][j] = __builtin_amdgcn_mfma_f32_16x16x32_f16(al[i], bh[j], acc[i][j], 0, 0, 0);
        acc[i][j] = __builtin_amdgcn_mfma_f32_16x16x32_f16(ah[i], bl[j], acc[i][j], 0, 0, 0);
        acc[i][j] = __builtin_amdgcn_mfma_f32_16x16x32_f16(ah[i], bh[j], acc[i][j], 0, 0, 0);
      }
  }
#pragma unroll
  for (int i = 0; i < 2; ++i) {
    int sp = s0 + i * 16 + quad * 4;
#pragma unroll
    for (int j = 0; j < 4; ++j) {
      int col = wv * 64 + j * 16 + ml;
      float bias = bo[col];
      size_t o = (((size_t)(b * 256 + col)) << 15) + sp;
      float4 xv = *(const float4*)(x + o);
      float4 ov;
      ov.x = acc[i][j][0] + bias + xv.x;
      ov.y = acc[i][j][1] + bias + xv.y;
      ov.z = acc[i][j][2] + bias + xv.z;
      ov.w = acc[i][j][3] + bias + xv.w;
      *(float4*)(out + o) = ov;
    }
  }
}

extern "C" void kernel_launch(void* const* d_in, const int* in_sizes, int n_in,
                              void* d_out, int out_size, void* d_ws, size_t ws_size,
                              hipStream_t stream) {
  (void)out_size; (void)ws_size;
  int idx[11] = {0, 1, 2, 3, 4, 5, 6, 7, 8, 9, 10};  // x,ctx,gng,gnb,lng,lnb,Wq,Wk,Wv,Wo,bo
  static const int dsz[11] = {16777216, 118272, 256, 256, 768, 768,
                              65536, 196608, 196608, 65536, 256};
  bool dict = (n_in == 11);
  if (dict)
    for (int i = 0; i < 11; ++i)
      if (in_sizes[i] != dsz[i]) { dict = false; break; }
  if (!dict && n_in == 11) {
    static const int ssz[11] = {196608, 65536, 65536, 196608, 256, 118272,
                                256, 256, 768, 768, 16777216};
    bool srt = true;
    for (int i = 0; i < 11; ++i)
      if (in_sizes[i] != ssz[i]) { srt = false; break; }
    if (srt) {
      idx[0] = 10; idx[1] = 5; idx[2] = 7; idx[3] = 6; idx[4] = 9; idx[5] = 8;
      idx[6] = 2;  idx[7] = 0; idx[8] = 3; idx[9] = 1; idx[10] = 4;
    }
  }
  const float* x   = (const float*)d_in[idx[0]];
  const float* ctx = (const float*)d_in[idx[1]];
  const float* gng = (const float*)d_in[idx[2]];
  const float* gnb = (const float*)d_in[idx[3]];
  const float* lng = (const float*)d_in[idx[4]];
  const float* lnb = (const float*)d_in[idx[5]];
  const float* Wq  = (const float*)d_in[idx[6]];
  const float* Wk  = (const float*)d_in[idx[7]];
  const float* Wv  = (const float*)d_in[idx[8]];
  const float* Wo  = (const float*)d_in[idx[9]];
  const float* bo  = (const float*)d_in[idx[10]];
  float* out = (float*)d_out;

  u16* ws = (u16*)d_ws;
  float* stats = (float*)ws;  // 512 floats: gsum[g] at g*16, gsq[g] at 256+g*16
  u16* wqt_hi = ws + 1024;
  u16* wqt_lo = wqt_hi + 65536;
  u16* wot_hi = wqt_lo + 65536;
  u16* wot_lo = wot_hi + 65536;
  u16* kws_hi = wot_lo + 65536;
  u16* kws_lo = kws_hi + 49152;
  u16* vtw_hi = kws_lo + 49152;
  u16* vtw_lo = vtw_hi + 49152;

  hipMemsetAsync(stats, 0, 512 * sizeof(float), stream);
  prep_all<<<2752, 256, 0, stream>>>(x, stats, ctx, lng, lnb, Wk, Wv,
                                     kws_hi, kws_lo, vtw_hi, vtw_lo,
                                     Wq, Wo, wqt_hi, wqt_lo, wot_hi, wot_lo);
  fused_qao<<<2048, 256, 0, stream>>>(x, wqt_hi, wqt_lo, wot_hi, wot_lo,
                                      kws_hi, kws_lo, vtw_hi, vtw_lo,
                                      gng, gnb, stats, bo, out);
}

// Round 6
// 264.904 us; speedup vs baseline: 1.4286x; 1.3003x over previous
//
#include <hip/hip_runtime.h>
#include <stdint.h>

typedef unsigned short u16;
typedef unsigned int u32;
typedef _Float16 half8 __attribute__((ext_vector_type(8)));
typedef _Float16 half4 __attribute__((ext_vector_type(4)));
typedef float floatx4 __attribute__((ext_vector_type(4)));

__device__ __forceinline__ void splitf(float a, u16* hi, u16* lo) {
  union { _Float16 h; u16 u; } ch, cl;
  ch.h = (_Float16)a;
  cl.h = (_Float16)(a - (float)ch.h);
  *hi = ch.u; *lo = cl.u;
}

// XOR-swizzled LDS index for the [64 row][256 col] u16 tile (row stride 512B).
// Row stride 512B == bank-aligned, so granule ^= row&7 spreads the 16B granules
// across banks (T2). All b128 reads use 8-aligned cols -> swizzle-safe.
__device__ __forceinline__ int qix(int row, int col) {
  return row * 256 + ((((col >> 3) ^ (row & 7)) << 3) | (col & 7));
}

// ---------------- merged prep kernel (unchanged) ----------------
__global__ void prep_all(const float* __restrict__ x, float* __restrict__ stats,
                         const float* __restrict__ ctx, const float* __restrict__ lng,
                         const float* __restrict__ lnb, const float* __restrict__ Wk,
                         const float* __restrict__ Wv,
                         u16* __restrict__ kh, u16* __restrict__ kl,
                         u16* __restrict__ vh, u16* __restrict__ vl,
                         const float* __restrict__ wq, const float* __restrict__ wo,
                         u16* __restrict__ wqt_hi, u16* __restrict__ wqt_lo,
                         u16* __restrict__ wot_hi, u16* __restrict__ wot_lo) {
  __shared__ float smem[776];
  int bid = blockIdx.x;
  int t = threadIdx.x;

  if (bid < 2048) {
    int bg = bid >> 7;
    int chunk = bid & 127;
    size_t base = ((size_t)bg << 20) + ((size_t)chunk << 13);
    float4 v[8];
#pragma unroll
    for (int it = 0; it < 8; ++it)
      v[it] = *(const float4*)(x + base + (size_t)it * 1024 + t * 4);
    float s = 0.f, sq = 0.f;
#pragma unroll
    for (int it = 0; it < 8; ++it) {
      s += v[it].x + v[it].y + v[it].z + v[it].w;
      sq += v[it].x * v[it].x + v[it].y * v[it].y + v[it].z * v[it].z + v[it].w * v[it].w;
    }
    for (int d = 32; d; d >>= 1) { s += __shfl_xor(s, d, 64); sq += __shfl_xor(sq, d, 64); }
    float* red = smem;
    int wv = t >> 6, lane = t & 63;
    if (lane == 0) { red[wv] = s; red[4 + wv] = sq; }
    __syncthreads();
    if (t == 0) {
      atomicAdd(&stats[bg * 16], red[0] + red[1] + red[2] + red[3]);
      atomicAdd(&stats[256 + bg * 16], red[4] + red[5] + red[6] + red[7]);
    }
    return;
  }

  if (bid < 2240) {
    int kb = bid - 2048;
    int key = kb % 96;
    int b = kb / 96;
    size_t ko = (size_t)(b * 96 + key) * 256 + t;
    size_t vo = ((size_t)(b * 8 + (t >> 5)) * 32 + (t & 31)) * 96 + key;
    if (key >= 77) {
      kh[ko] = 0; kl[ko] = 0; vh[vo] = 0; vl[vo] = 0;
      return;
    }
    float* lnv = smem;
    float* red = smem + 768;
    const float* row = ctx + (size_t)(b * 77 + key) * 768;
    float v0 = row[t], v1 = row[t + 256], v2 = row[t + 512];
    float s = v0 + v1 + v2, sq = v0 * v0 + v1 * v1 + v2 * v2;
    for (int d = 32; d; d >>= 1) { s += __shfl_xor(s, d, 64); sq += __shfl_xor(sq, d, 64); }
    int wv = t >> 6, lane = t & 63;
    if (!lane) { red[wv] = s; red[4 + wv] = sq; }
    __syncthreads();
    float S = red[0] + red[1] + red[2] + red[3];
    float SQ = red[4] + red[5] + red[6] + red[7];
    const float invD = 1.0f / 768.0f;
    float mean = S * invD;
    float rstd = rsqrtf(SQ * invD - mean * mean + 1e-5f);
    lnv[t]       = (v0 - mean) * rstd * lng[t]       + lnb[t];
    lnv[t + 256] = (v1 - mean) * rstd * lng[t + 256] + lnb[t + 256];
    lnv[t + 512] = (v2 - mean) * rstd * lng[t + 512] + lnb[t + 512];
    __syncthreads();
    float a0 = 0.f, a1 = 0.f, a2 = 0.f, a3 = 0.f;
    float c0 = 0.f, c1 = 0.f, c2 = 0.f, c3 = 0.f;
    for (int e = 0; e < 768; e += 4) {
      float w0 = lnv[e], w1 = lnv[e + 1], w2 = lnv[e + 2], w3 = lnv[e + 3];
      a0 += w0 * Wk[(e) * 256 + t];     a1 += w1 * Wk[(e + 1) * 256 + t];
      a2 += w2 * Wk[(e + 2) * 256 + t]; a3 += w3 * Wk[(e + 3) * 256 + t];
      c0 += w0 * Wv[(e) * 256 + t];     c1 += w1 * Wv[(e + 1) * 256 + t];
      c2 += w2 * Wv[(e + 2) * 256 + t]; c3 += w3 * Wv[(e + 3) * 256 + t];
    }
    float ak = (a0 + a1) + (a2 + a3);
    float av = (c0 + c1) + (c2 + c3);
    splitf(ak, &kh[ko], &kl[ko]);
    splitf(av, &vh[vo], &vl[vo]);
    return;
  }

  {
    int pb = bid - 2240;
    int bx = pb & 15, by = (pb >> 4) & 15, bz = pb >> 8;
    float (*tile)[17] = (float(*)[17])smem;
    const float* src = bz ? wo : wq;
    u16* dhi = bz ? wot_hi : wqt_hi;
    u16* dlo = bz ? wot_lo : wqt_lo;
    int r0 = by * 16, c0 = bx * 16;
    int r = t >> 4, c = t & 15;
    tile[r][c] = src[(r0 + r) * 256 + c0 + c];
    __syncthreads();
    float a = tile[c][r];
    int o = (c0 + r) * 256 + r0 + c;
    splitf(a, &dhi[o], &dlo[o]);
  }
}

// ---------------- fused Q-proj + attention + out-proj ----------------
// grid 1024: b = blk>>9, s0 = (blk&511)*64. 256 threads = 4 waves.
// Round-6: 64-row s-tile per block (2x round-5). Rounds 0-5 proved time is
// INVARIANT to occupancy (22->40% at fixed 219us) -> the constraint is
// per-output issue work (VMEM/DS instruction count), not latency hiding.
// Doubling the tile halves weight + K/V loads per output (~40% fewer VMEM
// instr chip-wide), halves barriers per output. LDS = 64x256x2Bx2 = 64KB
// exactly (XOR swizzle instead of pad; 2 blocks/CU). Arithmetic per output
// identical to round 5 -> absmax must stay 0.015625.
__global__ __launch_bounds__(256, 2) void fused_qao(
    const float* __restrict__ x,
    const u16* __restrict__ wqt_hi, const u16* __restrict__ wqt_lo,
    const u16* __restrict__ wot_hi, const u16* __restrict__ wot_lo,
    const u16* __restrict__ kws_hi, const u16* __restrict__ kws_lo,
    const u16* __restrict__ vtw_hi, const u16* __restrict__ vtw_lo,
    const float* __restrict__ gng, const float* __restrict__ gnb,
    const float* __restrict__ stats,
    const float* __restrict__ bo, float* __restrict__ out) {
  __shared__ u16 qhi[64 * 256];  // GN(x)^T tile; then Q; then attn_out (swizzled)
  __shared__ u16 qlo[64 * 256];
  int t = threadIdx.x, lane = t & 63, wv = t >> 6;
  int ml = lane & 15, quad = lane >> 4;
  int b = blockIdx.x >> 9;
  int s0 = (blockIdx.x & 511) * 64;

  // ---- Stage GN(x)^T tile [64 s][256 c] into qs (hi/lo), finalize GN inline.
  {
    const float invN = 1.0f / 1048576.0f;
    int sc_ = (t & 7) * 8;  // 8 consecutive s per thread
#pragma unroll
    for (int p = 0; p < 8; ++p) {
      int c = p * 32 + (t >> 3);
      int bg = b * 8 + (c >> 5);
      float mean = stats[bg * 16] * invN;
      float var = stats[256 + bg * 16] * invN - mean * mean;
      float rstd = rsqrtf(var + 1e-5f);
      float scale = rstd * gng[c];
      float shift = gnb[c] - mean * scale;
      size_t base = (((size_t)(b * 256 + c)) << 15) + s0 + sc_;
      float4 xv0 = *(const float4*)(x + base);
      float4 xv1 = *(const float4*)(x + base + 4);
      float xa[8] = {xv0.x, xv0.y, xv0.z, xv0.w, xv1.x, xv1.y, xv1.z, xv1.w};
#pragma unroll
      for (int e = 0; e < 8; ++e) {
        int o = qix(sc_ + e, c);
        splitf(xa[e] * scale + shift, &qhi[o], &qlo[o]);
      }
    }
  }
  __syncthreads();

  // ---- Step A: Q[64][256] = A-tile @ Wq^T. 4 row-blocks x 4 col-blocks/wave.
  floatx4 acc[4][4];
#pragma unroll
  for (int i = 0; i < 4; ++i)
#pragma unroll
    for (int j = 0; j < 4; ++j) acc[i][j] = (floatx4){0.f, 0.f, 0.f, 0.f};
  for (int k0 = 0; k0 < 256; k0 += 32) {
    half8 ah[4], al[4], bh[4], bl[4];
#pragma unroll
    for (int j = 0; j < 4; ++j) {
      size_t wo_ = (size_t)(wv * 64 + j * 16 + ml) * 256 + k0 + quad * 8;
      bh[j] = *(const half8*)(wqt_hi + wo_);
      bl[j] = *(const half8*)(wqt_lo + wo_);
    }
#pragma unroll
    for (int i = 0; i < 4; ++i) {
      int idx = qix(i * 16 + ml, k0 + quad * 8);
      ah[i] = *(const half8*)&qhi[idx];
      al[i] = *(const half8*)&qlo[idx];
    }
#pragma unroll
    for (int i = 0; i < 4; ++i)
#pragma unroll
      for (int j = 0; j < 4; ++j) {
        acc[i][j] = __builtin_amdgcn_mfma_f32_16x16x32_f16(al[i], bh[j], acc[i][j], 0, 0, 0);
        acc[i][j] = __builtin_amdgcn_mfma_f32_16x16x32_f16(ah[i], bl[j], acc[i][j], 0, 0, 0);
        acc[i][j] = __builtin_amdgcn_mfma_f32_16x16x32_f16(ah[i], bh[j], acc[i][j], 0, 0, 0);
      }
  }
  __syncthreads();  // all waves done reading A-tile before overwriting with Q
#pragma unroll
  for (int i = 0; i < 4; ++i)
#pragma unroll
    for (int j = 0; j < 4; ++j)
#pragma unroll
      for (int r = 0; r < 4; ++r) {
        int o = qix(i * 16 + quad * 4 + r, wv * 64 + j * 16 + ml);
        splitf(acc[i][j][r], &qhi[o], &qlo[o]);
      }
  __syncthreads();  // Q complete (cross-wave columns)

  // ---- Step B: attention, in-register P (swapped QK^T).
  // wave -> heads (wv>>1)*4.., row-halves r16=(wv&1)*16; two row-groups
  // rg in {0,1} (rows rg*32 + r16 ..) reuse the SAME K/V registers.
  int h0 = (wv >> 1) * 4;
  int r16 = (wv & 1) * 16;
  const float scl = 0.17677669529663687f;
  const floatx4 z = {0.f, 0.f, 0.f, 0.f};
  for (int hh = 0; hh < 4; ++hh) {
    int h = h0 + hh;
    half8 kbh[5], kbl[5];
#pragma unroll
    for (int kt = 0; kt < 5; ++kt) {
      size_t ko = (size_t)(b * 96 + kt * 16 + ml) * 256 + h * 32 + quad * 8;
      kbh[kt] = *(const half8*)(kws_hi + ko);
      kbl[kt] = *(const half8*)(kws_lo + ko);
    }
    half4 vfh[2][5], vfl[2][5];
#pragma unroll
    for (int db = 0; db < 2; ++db)
#pragma unroll
      for (int kt = 0; kt < 5; ++kt) {
        size_t vo = (size_t)((b * 8 + h) * 32 + db * 16 + ml) * 96 + kt * 16 + quad * 4;
        vfh[db][kt] = *(const half4*)(vtw_hi + vo);
        vfl[db][kt] = *(const half4*)(vtw_lo + vo);
      }
#pragma unroll
    for (int rg = 0; rg < 2; ++rg) {
      int qrow = rg * 32 + r16 + ml;
      int qidx0 = qix(qrow, h * 32 + quad * 8);
      half8 qfh = *(const half8*)&qhi[qidx0];
      half8 qfl = *(const half8*)&qlo[qidx0];
      // S^T = K x Q^T: lane holds S^T[key=kt*16+quad*4+r][q=qrow]
      floatx4 sc[5];
      __builtin_amdgcn_s_setprio(1);
#pragma unroll
      for (int kt = 0; kt < 5; ++kt) {
        floatx4 a = __builtin_amdgcn_mfma_f32_16x16x32_f16(kbl[kt], qfh, z, 0, 0, 0);
        a = __builtin_amdgcn_mfma_f32_16x16x32_f16(kbh[kt], qfl, a, 0, 0, 0);
        sc[kt] = __builtin_amdgcn_mfma_f32_16x16x32_f16(kbh[kt], qfh, a, 0, 0, 0);
      }
      __builtin_amdgcn_s_setprio(0);
      // softmax over keys, per q: scalar + 2 shfl rounds across quads.
      float mx = -1e30f;
#pragma unroll
      for (int kt = 0; kt < 5; ++kt) {
        int kbase = kt * 16 + quad * 4;
#pragma unroll
        for (int r = 0; r < 4; ++r) {
          float v = (kbase + r < 77) ? sc[kt][r] * scl : -1e30f;
          sc[kt][r] = v;
          mx = fmaxf(mx, v);
        }
      }
      mx = fmaxf(mx, __shfl_xor(mx, 16, 64));
      mx = fmaxf(mx, __shfl_xor(mx, 32, 64));
      float sm = 0.f;
#pragma unroll
      for (int kt = 0; kt < 5; ++kt)
#pragma unroll
        for (int r = 0; r < 4; ++r) {
          float p = __expf(sc[kt][r] - mx);
          sc[kt][r] = p;
          sm += p;
        }
      sm += __shfl_xor(sm, 16, 64);
      sm += __shfl_xor(sm, 32, 64);
      float inv = 1.0f / sm;
      half4 pb[5];
#pragma unroll
      for (int kt = 0; kt < 5; ++kt) {
        pb[kt][0] = (_Float16)(sc[kt][0] * inv);
        pb[kt][1] = (_Float16)(sc[kt][1] * inv);
        pb[kt][2] = (_Float16)(sc[kt][2] * inv);
        pb[kt][3] = (_Float16)(sc[kt][3] * inv);
      }
      // PV^T via 16x16x16 MFMAs, P straight from registers.
      floatx4 o0 = z, o1 = z;
      __builtin_amdgcn_s_setprio(1);
#pragma unroll
      for (int kt = 0; kt < 5; ++kt) {
        o0 = __builtin_amdgcn_mfma_f32_16x16x16f16(vfl[0][kt], pb[kt], o0, 0, 0, 0);
        o0 = __builtin_amdgcn_mfma_f32_16x16x16f16(vfh[0][kt], pb[kt], o0, 0, 0, 0);
        o1 = __builtin_amdgcn_mfma_f32_16x16x16f16(vfl[1][kt], pb[kt], o1, 0, 0, 0);
        o1 = __builtin_amdgcn_mfma_f32_16x16x16f16(vfh[1][kt], pb[kt], o1, 0, 0, 0);
      }
      __builtin_amdgcn_s_setprio(0);
      // lane holds attn_out[q=qrow][d = db*16 + quad*4 + r]
#pragma unroll
      for (int r = 0; r < 4; ++r) {
        int o0i = qix(qrow, h * 32 + quad * 4 + r);
        splitf(o0[r], &qhi[o0i], &qlo[o0i]);
        int o1i = qix(qrow, h * 32 + 16 + quad * 4 + r);
        splitf(o1[r], &qhi[o1i], &qlo[o1i]);
      }
    }
  }
  __syncthreads();  // attn_out complete before Step C reads all columns

  // ---- Step C: out = attn_out @ Wo^T + bo + x.
#pragma unroll
  for (int i = 0; i < 4; ++i)
#pragma unroll
    for (int j = 0; j < 4; ++j) acc[i][j] = (floatx4){0.f, 0.f, 0.f, 0.f};
  for (int k0 = 0; k0 < 256; k0 += 32) {
    half8 ah[4], al[4], bh[4], bl[4];
#pragma unroll
    for (int j = 0; j < 4; ++j) {
      size_t wo_ = (size_t)(wv * 64 + j * 16 + ml) * 256 + k0 + quad * 8;
      bh[j] = *(const half8*)(wot_hi + wo_);
      bl[j] = *(const half8*)(wot_lo + wo_);
    }
#pragma unroll
    for (int i = 0; i < 4; ++i) {
      int idx = qix(i * 16 + ml, k0 + quad * 8);
      ah[i] = *(const half8*)&qhi[idx];
      al[i] = *(const half8*)&qlo[idx];
    }
#pragma unroll
    for (int i = 0; i < 4; ++i)
#pragma unroll
      for (int j = 0; j < 4; ++j) {
        acc[i][j] = __builtin_amdgcn_mfma_f32_16x16x32_f16(al[i], bh[j], acc[i][j], 0, 0, 0);
        acc[i][j] = __builtin_amdgcn_mfma_f32_16x16x32_f16(ah[i], bl[j], acc[i][j], 0, 0, 0);
        acc[i][j] = __builtin_amdgcn_mfma_f32_16x16x32_f16(ah[i], bh[j], acc[i][j], 0, 0, 0);
      }
  }
#pragma unroll
  for (int i = 0; i < 4; ++i) {
    int sp = s0 + i * 16 + quad * 4;
#pragma unroll
    for (int j = 0; j < 4; ++j) {
      int col = wv * 64 + j * 16 + ml;
      float bias = bo[col];
      size_t o = (((size_t)(b * 256 + col)) << 15) + sp;
      float4 xv = *(const float4*)(x + o);
      float4 ov;
      ov.x = acc[i][j][0] + bias + xv.x;
      ov.y = acc[i][j][1] + bias + xv.y;
      ov.z = acc[i][j][2] + bias + xv.z;
      ov.w = acc[i][j][3] + bias + xv.w;
      *(float4*)(out + o) = ov;
    }
  }
}

extern "C" void kernel_launch(void* const* d_in, const int* in_sizes, int n_in,
                              void* d_out, int out_size, void* d_ws, size_t ws_size,
                              hipStream_t stream) {
  (void)out_size; (void)ws_size;
  int idx[11] = {0, 1, 2, 3, 4, 5, 6, 7, 8, 9, 10};  // x,ctx,gng,gnb,lng,lnb,Wq,Wk,Wv,Wo,bo
  static const int dsz[11] = {16777216, 118272, 256, 256, 768, 768,
                              65536, 196608, 196608, 65536, 256};
  bool dict = (n_in == 11);
  if (dict)
    for (int i = 0; i < 11; ++i)
      if (in_sizes[i] != dsz[i]) { dict = false; break; }
  if (!dict && n_in == 11) {
    static const int ssz[11] = {196608, 65536, 65536, 196608, 256, 118272,
                                256, 256, 768, 768, 16777216};
    bool srt = true;
    for (int i = 0; i < 11; ++i)
      if (in_sizes[i] != ssz[i]) { srt = false; break; }
    if (srt) {
      idx[0] = 10; idx[1] = 5; idx[2] = 7; idx[3] = 6; idx[4] = 9; idx[5] = 8;
      idx[6] = 2;  idx[7] = 0; idx[8] = 3; idx[9] = 1; idx[10] = 4;
    }
  }
  const float* x   = (const float*)d_in[idx[0]];
  const float* ctx = (const float*)d_in[idx[1]];
  const float* gng = (const float*)d_in[idx[2]];
  const float* gnb = (const float*)d_in[idx[3]];
  const float* lng = (const float*)d_in[idx[4]];
  const float* lnb = (const float*)d_in[idx[5]];
  const float* Wq  = (const float*)d_in[idx[6]];
  const float* Wk  = (const float*)d_in[idx[7]];
  const float* Wv  = (const float*)d_in[idx[8]];
  const float* Wo  = (const float*)d_in[idx[9]];
  const float* bo  = (const float*)d_in[idx[10]];
  float* out = (float*)d_out;

  u16* ws = (u16*)d_ws;
  float* stats = (float*)ws;  // 512 floats: gsum[g] at g*16, gsq[g] at 256+g*16
  u16* wqt_hi = ws + 1024;
  u16* wqt_lo = wqt_hi + 65536;
  u16* wot_hi = wqt_lo + 65536;
  u16* wot_lo = wot_hi + 65536;
  u16* kws_hi = wot_lo + 65536;
  u16* kws_lo = kws_hi + 49152;
  u16* vtw_hi = kws_lo + 49152;
  u16* vtw_lo = vtw_hi + 49152;

  hipMemsetAsync(stats, 0, 512 * sizeof(float), stream);
  prep_all<<<2752, 256, 0, stream>>>(x, stats, ctx, lng, lnb, Wk, Wv,
                                     kws_hi, kws_lo, vtw_hi, vtw_lo,
                                     Wq, Wo, wqt_hi, wqt_lo, wot_hi, wot_lo);
  fused_qao<<<1024, 256, 0, stream>>>(x, wqt_hi, wqt_lo, wot_hi, wot_lo,
                                      kws_hi, kws_lo, vtw_hi, vtw_lo,
                                      gng, gnb, stats, bo, out);
}

// Round 7
// 251.328 us; speedup vs baseline: 1.5058x; 1.0540x over previous
//
#include <hip/hip_runtime.h>
#include <stdint.h>

typedef unsigned short u16;
typedef unsigned int u32;
typedef _Float16 half8 __attribute__((ext_vector_type(8)));
typedef _Float16 half4 __attribute__((ext_vector_type(4)));
typedef float floatx4 __attribute__((ext_vector_type(4)));

__device__ __forceinline__ void splitf(float a, u16* hi, u16* lo) {
  union { _Float16 h; u16 u; } ch, cl;
  ch.h = (_Float16)a;
  cl.h = (_Float16)(a - (float)ch.h);
  *hi = ch.u; *lo = cl.u;
}

__device__ __forceinline__ u16 cvt16(float a) {
  union { _Float16 h; u16 u; } c;
  c.h = (_Float16)a;
  return c.u;
}

// XOR-swizzled LDS index for the [64 row][256 col] u16 tile (row stride 512B).
// granule ^= (row&7) ^ ((row>>3)&7): the second term breaks the round-6
// staging-write pathology (all 64 lanes in one granule). b128 reads keep
// 8-aligned cols -> swizzle-safe, aliasing <= 2-way (free, m136).
__device__ __forceinline__ int qix(int row, int col) {
  int g = (col >> 3) ^ (row & 7) ^ ((row >> 3) & 7);
  return row * 256 + ((g << 3) | (col & 7));
}

// ---------------- merged prep kernel ----------------
// grid 2944 blocks x 256:
//   [0,2048)     gn_partial (GroupNorm partial sums; 8 float4/thread in flight)
//   [2048,2432)  ln_kv split: 192 K-blocks then 192 V-blocks (halved serial
//                chain per block; single-plane fp16 stores)
//   [2432,2944)  prep_w (transpose Wq/Wo into split fp16 planes [n][k])
__global__ void prep_all(const float* __restrict__ x, float* __restrict__ stats,
                         const float* __restrict__ ctx, const float* __restrict__ lng,
                         const float* __restrict__ lnb, const float* __restrict__ Wk,
                         const float* __restrict__ Wv,
                         u16* __restrict__ kh, u16* __restrict__ vh,
                         const float* __restrict__ wq, const float* __restrict__ wo,
                         u16* __restrict__ wqt_hi, u16* __restrict__ wqt_lo,
                         u16* __restrict__ wot_hi, u16* __restrict__ wot_lo) {
  __shared__ float smem[776];
  int bid = blockIdx.x;
  int t = threadIdx.x;

  if (bid < 2048) {
    int bg = bid >> 7;
    int chunk = bid & 127;
    size_t base = ((size_t)bg << 20) + ((size_t)chunk << 13);
    float4 v[8];
#pragma unroll
    for (int it = 0; it < 8; ++it)
      v[it] = *(const float4*)(x + base + (size_t)it * 1024 + t * 4);
    float s = 0.f, sq = 0.f;
#pragma unroll
    for (int it = 0; it < 8; ++it) {
      s += v[it].x + v[it].y + v[it].z + v[it].w;
      sq += v[it].x * v[it].x + v[it].y * v[it].y + v[it].z * v[it].z + v[it].w * v[it].w;
    }
    for (int d = 32; d; d >>= 1) { s += __shfl_xor(s, d, 64); sq += __shfl_xor(sq, d, 64); }
    float* red = smem;
    int wv = t >> 6, lane = t & 63;
    if (lane == 0) { red[wv] = s; red[4 + wv] = sq; }
    __syncthreads();
    if (t == 0) {
      atomicAdd(&stats[bg * 16], red[0] + red[1] + red[2] + red[3]);
      atomicAdd(&stats[256 + bg * 16], red[4] + red[5] + red[6] + red[7]);
    }
    return;
  }

  if (bid < 2432) {
    // ---- ln_kv, split into K-blocks and V-blocks ----
    int kb = bid - 2048;
    int doV = kb >= 192;
    if (doV) kb -= 192;
    int key = kb % 96;
    int b = kb / 96;
    size_t ko = (size_t)(b * 96 + key) * 256 + t;
    size_t vo = ((size_t)(b * 8 + (t >> 5)) * 32 + (t & 31)) * 96 + key;
    if (key >= 77) {
      if (doV) vh[vo] = 0; else kh[ko] = 0;
      return;
    }
    float* lnv = smem;
    float* red = smem + 768;
    const float* row = ctx + (size_t)(b * 77 + key) * 768;
    float v0 = row[t], v1 = row[t + 256], v2 = row[t + 512];
    float s = v0 + v1 + v2, sq = v0 * v0 + v1 * v1 + v2 * v2;
    for (int d = 32; d; d >>= 1) { s += __shfl_xor(s, d, 64); sq += __shfl_xor(sq, d, 64); }
    int wv = t >> 6, lane = t & 63;
    if (!lane) { red[wv] = s; red[4 + wv] = sq; }
    __syncthreads();
    float S = red[0] + red[1] + red[2] + red[3];
    float SQ = red[4] + red[5] + red[6] + red[7];
    const float invD = 1.0f / 768.0f;
    float mean = S * invD;
    float rstd = rsqrtf(SQ * invD - mean * mean + 1e-5f);
    lnv[t]       = (v0 - mean) * rstd * lng[t]       + lnb[t];
    lnv[t + 256] = (v1 - mean) * rstd * lng[t + 256] + lnb[t + 256];
    lnv[t + 512] = (v2 - mean) * rstd * lng[t + 512] + lnb[t + 512];
    __syncthreads();
    const float* W = doV ? Wv : Wk;
    float a0 = 0.f, a1 = 0.f, a2 = 0.f, a3 = 0.f;
    float a4 = 0.f, a5 = 0.f, a6 = 0.f, a7 = 0.f;
    for (int e = 0; e < 768; e += 8) {
      a0 += lnv[e] * W[(e) * 256 + t];         a1 += lnv[e + 1] * W[(e + 1) * 256 + t];
      a2 += lnv[e + 2] * W[(e + 2) * 256 + t]; a3 += lnv[e + 3] * W[(e + 3) * 256 + t];
      a4 += lnv[e + 4] * W[(e + 4) * 256 + t]; a5 += lnv[e + 5] * W[(e + 5) * 256 + t];
      a6 += lnv[e + 6] * W[(e + 6) * 256 + t]; a7 += lnv[e + 7] * W[(e + 7) * 256 + t];
    }
    float a = ((a0 + a1) + (a2 + a3)) + ((a4 + a5) + (a6 + a7));
    if (doV) vh[vo] = cvt16(a); else kh[ko] = cvt16(a);
    return;
  }

  // ---- prep_w ----
  {
    int pb = bid - 2432;
    int bx = pb & 15, by = (pb >> 4) & 15, bz = pb >> 8;
    float (*tile)[17] = (float(*)[17])smem;
    const float* src = bz ? wo : wq;
    u16* dhi = bz ? wot_hi : wqt_hi;
    u16* dlo = bz ? wot_lo : wqt_lo;
    int r0 = by * 16, c0 = bx * 16;
    int r = t >> 4, c = t & 15;
    tile[r][c] = src[(r0 + r) * 256 + c0 + c];
    __syncthreads();
    float a = tile[c][r];
    int o = (c0 + r) * 256 + r0 + c;
    splitf(a, &dhi[o], &dlo[o]);
  }
}

// ---------------- fused Q-proj + attention + out-proj ----------------
// grid 1024: b = blk>>9, s0 = (blk&511)*64. 256 threads = 4 waves.
// Round-7: attention path single-plane fp16 (K, V, Q-frag hi only; error
// budget ~5e-4 abs vs 0.0156 current absmax). Step B MFMAs 280->120/wave,
// K/V loads halved. Steps A/C keep the hi/lo split GEMM. qix gains the
// (row>>3) XOR to fix staging-write bank conflicts (10.5M in round 6).
__global__ __launch_bounds__(256, 2) void fused_qao(
    const float* __restrict__ x,
    const u16* __restrict__ wqt_hi, const u16* __restrict__ wqt_lo,
    const u16* __restrict__ wot_hi, const u16* __restrict__ wot_lo,
    const u16* __restrict__ kws_hi, const u16* __restrict__ vtw_hi,
    const float* __restrict__ gng, const float* __restrict__ gnb,
    const float* __restrict__ stats,
    const float* __restrict__ bo, float* __restrict__ out) {
  __shared__ u16 qhi[64 * 256];  // GN(x)^T tile; then Q(hi); then attn_out
  __shared__ u16 qlo[64 * 256];  // GN lo; stale during attn; then attn_out lo
  int t = threadIdx.x, lane = t & 63, wv = t >> 6;
  int ml = lane & 15, quad = lane >> 4;
  int b = blockIdx.x >> 9;
  int s0 = (blockIdx.x & 511) * 64;

  // ---- Stage GN(x)^T tile [64 s][256 c] into qs (hi/lo), finalize GN inline.
  {
    const float invN = 1.0f / 1048576.0f;
    int sc_ = (t & 7) * 8;  // 8 consecutive s per thread
#pragma unroll
    for (int p = 0; p < 8; ++p) {
      int c = p * 32 + (t >> 3);
      int bg = b * 8 + (c >> 5);
      float mean = stats[bg * 16] * invN;
      float var = stats[256 + bg * 16] * invN - mean * mean;
      float rstd = rsqrtf(var + 1e-5f);
      float scale = rstd * gng[c];
      float shift = gnb[c] - mean * scale;
      size_t base = (((size_t)(b * 256 + c)) << 15) + s0 + sc_;
      float4 xv0 = *(const float4*)(x + base);
      float4 xv1 = *(const float4*)(x + base + 4);
      float xa[8] = {xv0.x, xv0.y, xv0.z, xv0.w, xv1.x, xv1.y, xv1.z, xv1.w};
#pragma unroll
      for (int e = 0; e < 8; ++e) {
        int o = qix(sc_ + e, c);
        splitf(xa[e] * scale + shift, &qhi[o], &qlo[o]);
      }
    }
  }
  __syncthreads();

  // ---- Step A: Q[64][256] = A-tile @ Wq^T. 4 row-blocks x 4 col-blocks/wave.
  floatx4 acc[4][4];
#pragma unroll
  for (int i = 0; i < 4; ++i)
#pragma unroll
    for (int j = 0; j < 4; ++j) acc[i][j] = (floatx4){0.f, 0.f, 0.f, 0.f};
  for (int k0 = 0; k0 < 256; k0 += 32) {
    half8 ah[4], al[4], bh[4], bl[4];
#pragma unroll
    for (int j = 0; j < 4; ++j) {
      size_t wo_ = (size_t)(wv * 64 + j * 16 + ml) * 256 + k0 + quad * 8;
      bh[j] = *(const half8*)(wqt_hi + wo_);
      bl[j] = *(const half8*)(wqt_lo + wo_);
    }
#pragma unroll
    for (int i = 0; i < 4; ++i) {
      int idx = qix(i * 16 + ml, k0 + quad * 8);
      ah[i] = *(const half8*)&qhi[idx];
      al[i] = *(const half8*)&qlo[idx];
    }
#pragma unroll
    for (int i = 0; i < 4; ++i)
#pragma unroll
      for (int j = 0; j < 4; ++j) {
        acc[i][j] = __builtin_amdgcn_mfma_f32_16x16x32_f16(al[i], bh[j], acc[i][j], 0, 0, 0);
        acc[i][j] = __builtin_amdgcn_mfma_f32_16x16x32_f16(ah[i], bl[j], acc[i][j], 0, 0, 0);
        acc[i][j] = __builtin_amdgcn_mfma_f32_16x16x32_f16(ah[i], bh[j], acc[i][j], 0, 0, 0);
      }
  }
  __syncthreads();  // all waves done reading A-tile before overwriting with Q
  // Q writeback: hi plane only (attention consumes fp16 Q; qlo is fully
  // overwritten by attn_out before Step C reads it).
#pragma unroll
  for (int i = 0; i < 4; ++i)
#pragma unroll
    for (int j = 0; j < 4; ++j)
#pragma unroll
      for (int r = 0; r < 4; ++r) {
        int o = qix(i * 16 + quad * 4 + r, wv * 64 + j * 16 + ml);
        qhi[o] = cvt16(acc[i][j][r]);
      }
  __syncthreads();  // Q complete (cross-wave columns)

  // ---- Step B: attention, in-register P, single-plane fp16 K/V/Q.
  int h0 = (wv >> 1) * 4;
  int r16 = (wv & 1) * 16;
  const float scl = 0.17677669529663687f;
  const floatx4 z = {0.f, 0.f, 0.f, 0.f};
  for (int hh = 0; hh < 4; ++hh) {
    int h = h0 + hh;
    half8 kbh[5];
#pragma unroll
    for (int kt = 0; kt < 5; ++kt) {
      size_t ko = (size_t)(b * 96 + kt * 16 + ml) * 256 + h * 32 + quad * 8;
      kbh[kt] = *(const half8*)(kws_hi + ko);
    }
    half4 vfh[2][5];
#pragma unroll
    for (int db = 0; db < 2; ++db)
#pragma unroll
      for (int kt = 0; kt < 5; ++kt) {
        size_t vo = (size_t)((b * 8 + h) * 32 + db * 16 + ml) * 96 + kt * 16 + quad * 4;
        vfh[db][kt] = *(const half4*)(vtw_hi + vo);
      }
#pragma unroll
    for (int rg = 0; rg < 2; ++rg) {
      int qrow = rg * 32 + r16 + ml;
      half8 qfh = *(const half8*)&qhi[qix(qrow, h * 32 + quad * 8)];
      // S^T = K x Q^T: lane holds S^T[key=kt*16+quad*4+r][q=qrow]
      floatx4 sc[5];
      __builtin_amdgcn_s_setprio(1);
#pragma unroll
      for (int kt = 0; kt < 5; ++kt)
        sc[kt] = __builtin_amdgcn_mfma_f32_16x16x32_f16(kbh[kt], qfh, z, 0, 0, 0);
      __builtin_amdgcn_s_setprio(0);
      // softmax over keys, per q: scalar + 2 shfl rounds across quads.
      float mx = -1e30f;
#pragma unroll
      for (int kt = 0; kt < 5; ++kt) {
        int kbase = kt * 16 + quad * 4;
#pragma unroll
        for (int r = 0; r < 4; ++r) {
          float v = (kbase + r < 77) ? sc[kt][r] * scl : -1e30f;
          sc[kt][r] = v;
          mx = fmaxf(mx, v);
        }
      }
      mx = fmaxf(mx, __shfl_xor(mx, 16, 64));
      mx = fmaxf(mx, __shfl_xor(mx, 32, 64));
      float sm = 0.f;
#pragma unroll
      for (int kt = 0; kt < 5; ++kt)
#pragma unroll
        for (int r = 0; r < 4; ++r) {
          float p = __expf(sc[kt][r] - mx);
          sc[kt][r] = p;
          sm += p;
        }
      sm += __shfl_xor(sm, 16, 64);
      sm += __shfl_xor(sm, 32, 64);
      float inv = 1.0f / sm;
      half4 pb[5];
#pragma unroll
      for (int kt = 0; kt < 5; ++kt) {
        pb[kt][0] = (_Float16)(sc[kt][0] * inv);
        pb[kt][1] = (_Float16)(sc[kt][1] * inv);
        pb[kt][2] = (_Float16)(sc[kt][2] * inv);
        pb[kt][3] = (_Float16)(sc[kt][3] * inv);
      }
      // PV^T via 16x16x16 MFMAs, P straight from registers.
      floatx4 o0 = z, o1 = z;
      __builtin_amdgcn_s_setprio(1);
#pragma unroll
      for (int kt = 0; kt < 5; ++kt) {
        o0 = __builtin_amdgcn_mfma_f32_16x16x16f16(vfh[0][kt], pb[kt], o0, 0, 0, 0);
        o1 = __builtin_amdgcn_mfma_f32_16x16x16f16(vfh[1][kt], pb[kt], o1, 0, 0, 0);
      }
      __builtin_amdgcn_s_setprio(0);
      // lane holds attn_out[q=qrow][d = db*16 + quad*4 + r] -> split write
      // (Step C consumes hi/lo).
#pragma unroll
      for (int r = 0; r < 4; ++r) {
        int o0i = qix(qrow, h * 32 + quad * 4 + r);
        splitf(o0[r], &qhi[o0i], &qlo[o0i]);
        int o1i = qix(qrow, h * 32 + 16 + quad * 4 + r);
        splitf(o1[r], &qhi[o1i], &qlo[o1i]);
      }
    }
  }
  __syncthreads();  // attn_out complete before Step C reads all columns

  // ---- Step C: out = attn_out @ Wo^T + bo + x.
#pragma unroll
  for (int i = 0; i < 4; ++i)
#pragma unroll
    for (int j = 0; j < 4; ++j) acc[i][j] = (floatx4){0.f, 0.f, 0.f, 0.f};
  for (int k0 = 0; k0 < 256; k0 += 32) {
    half8 ah[4], al[4], bh[4], bl[4];
#pragma unroll
    for (int j = 0; j < 4; ++j) {
      size_t wo_ = (size_t)(wv * 64 + j * 16 + ml) * 256 + k0 + quad * 8;
      bh[j] = *(const half8*)(wot_hi + wo_);
      bl[j] = *(const half8*)(wot_lo + wo_);
    }
#pragma unroll
    for (int i = 0; i < 4; ++i) {
      int idx = qix(i * 16 + ml, k0 + quad * 8);
      ah[i] = *(const half8*)&qhi[idx];
      al[i] = *(const half8*)&qlo[idx];
    }
#pragma unroll
    for (int i = 0; i < 4; ++i)
#pragma unroll
      for (int j = 0; j < 4; ++j) {
        acc[i][j] = __builtin_amdgcn_mfma_f32_16x16x32_f16(al[i], bh[j], acc[i][j], 0, 0, 0);
        acc[i][j] = __builtin_amdgcn_mfma_f32_16x16x32_f16(ah[i], bl[j], acc[i][j], 0, 0, 0);
        acc[i][j] = __builtin_amdgcn_mfma_f32_16x16x32_f16(ah[i], bh[j], acc[i][j], 0, 0, 0);
      }
  }
#pragma unroll
  for (int i = 0; i < 4; ++i) {
    int sp = s0 + i * 16 + quad * 4;
#pragma unroll
    for (int j = 0; j < 4; ++j) {
      int col = wv * 64 + j * 16 + ml;
      float bias = bo[col];
      size_t o = (((size_t)(b * 256 + col)) << 15) + sp;
      float4 xv = *(const float4*)(x + o);
      float4 ov;
      ov.x = acc[i][j][0] + bias + xv.x;
      ov.y = acc[i][j][1] + bias + xv.y;
      ov.z = acc[i][j][2] + bias + xv.z;
      ov.w = acc[i][j][3] + bias + xv.w;
      *(float4*)(out + o) = ov;
    }
  }
}

extern "C" void kernel_launch(void* const* d_in, const int* in_sizes, int n_in,
                              void* d_out, int out_size, void* d_ws, size_t ws_size,
                              hipStream_t stream) {
  (void)out_size; (void)ws_size;
  int idx[11] = {0, 1, 2, 3, 4, 5, 6, 7, 8, 9, 10};  // x,ctx,gng,gnb,lng,lnb,Wq,Wk,Wv,Wo,bo
  static const int dsz[11] = {16777216, 118272, 256, 256, 768, 768,
                              65536, 196608, 196608, 65536, 256};
  bool dict = (n_in == 11);
  if (dict)
    for (int i = 0; i < 11; ++i)
      if (in_sizes[i] != dsz[i]) { dict = false; break; }
  if (!dict && n_in == 11) {
    static const int ssz[11] = {196608, 65536, 65536, 196608, 256, 118272,
                                256, 256, 768, 768, 16777216};
    bool srt = true;
    for (int i = 0; i < 11; ++i)
      if (in_sizes[i] != ssz[i]) { srt = false; break; }
    if (srt) {
      idx[0] = 10; idx[1] = 5; idx[2] = 7; idx[3] = 6; idx[4] = 9; idx[5] = 8;
      idx[6] = 2;  idx[7] = 0; idx[8] = 3; idx[9] = 1; idx[10] = 4;
    }
  }
  const float* x   = (const float*)d_in[idx[0]];
  const float* ctx = (const float*)d_in[idx[1]];
  const float* gng = (const float*)d_in[idx[2]];
  const float* gnb = (const float*)d_in[idx[3]];
  const float* lng = (const float*)d_in[idx[4]];
  const float* lnb = (const float*)d_in[idx[5]];
  const float* Wq  = (const float*)d_in[idx[6]];
  const float* Wk  = (const float*)d_in[idx[7]];
  const float* Wv  = (const float*)d_in[idx[8]];
  const float* Wo  = (const float*)d_in[idx[9]];
  const float* bo  = (const float*)d_in[idx[10]];
  float* out = (float*)d_out;

  u16* ws = (u16*)d_ws;
  float* stats = (float*)ws;  // 512 floats: gsum[g] at g*16, gsq[g] at 256+g*16
  u16* wqt_hi = ws + 1024;
  u16* wqt_lo = wqt_hi + 65536;
  u16* wot_hi = wqt_lo + 65536;
  u16* wot_lo = wot_hi + 65536;
  u16* kws_hi = wot_lo + 65536;
  u16* vtw_hi = kws_hi + 49152;

  hipMemsetAsync(stats, 0, 512 * sizeof(float), stream);
  prep_all<<<2944, 256, 0, stream>>>(x, stats, ctx, lng, lnb, Wk, Wv,
                                     kws_hi, vtw_hi,
                                     Wq, Wo, wqt_hi, wqt_lo, wot_hi, wot_lo);
  fused_qao<<<1024, 256, 0, stream>>>(x, wqt_hi, wqt_lo, wot_hi, wot_lo,
                                      kws_hi, vtw_hi,
                                      gng, gnb, stats, bo, out);
}

// Round 8
// 222.485 us; speedup vs baseline: 1.7010x; 1.1296x over previous
//
#include <hip/hip_runtime.h>
#include <stdint.h>

typedef unsigned short u16;
typedef unsigned int u32;
typedef _Float16 half8 __attribute__((ext_vector_type(8)));
typedef _Float16 half4 __attribute__((ext_vector_type(4)));
typedef float floatx4 __attribute__((ext_vector_type(4)));

__device__ __forceinline__ void splitf(float a, u16* hi, u16* lo) {
  union { _Float16 h; u16 u; } ch, cl;
  ch.h = (_Float16)a;
  cl.h = (_Float16)(a - (float)ch.h);
  *hi = ch.u; *lo = cl.u;
}

__device__ __forceinline__ u16 cvt16(float a) {
  union { _Float16 h; u16 u; } c;
  c.h = (_Float16)a;
  return c.u;
}

// XOR-swizzled LDS index for the [64 row][256 col] u16 tile (row stride 512B).
// granule ^= (row&7) ^ ((row>>3)&7): second term breaks the staging-write
// pathology (round 6->7: conflicts 10.5M->3.1M, measured).
__device__ __forceinline__ int qix(int row, int col) {
  int g = (col >> 3) ^ (row & 7) ^ ((row >> 3) & 7);
  return row * 256 + ((g << 3) | (col & 7));
}

// ---------------- merged prep kernel ----------------
// grid 2944 blocks x 256:
//   [0,2048)     gn_partial (GroupNorm partial sums; 8 float4/thread in flight)
//   [2048,2432)  ln_kv split: 192 K-blocks then 192 V-blocks (single fp16)
//   [2432,2944)  prep_w (transpose Wq/Wo into SINGLE fp16 plane [n][k])
__global__ void prep_all(const float* __restrict__ x, float* __restrict__ stats,
                         const float* __restrict__ ctx, const float* __restrict__ lng,
                         const float* __restrict__ lnb, const float* __restrict__ Wk,
                         const float* __restrict__ Wv,
                         u16* __restrict__ kh, u16* __restrict__ vh,
                         const float* __restrict__ wq, const float* __restrict__ wo,
                         u16* __restrict__ wqt, u16* __restrict__ wot) {
  __shared__ float smem[776];
  int bid = blockIdx.x;
  int t = threadIdx.x;

  if (bid < 2048) {
    int bg = bid >> 7;
    int chunk = bid & 127;
    size_t base = ((size_t)bg << 20) + ((size_t)chunk << 13);
    float4 v[8];
#pragma unroll
    for (int it = 0; it < 8; ++it)
      v[it] = *(const float4*)(x + base + (size_t)it * 1024 + t * 4);
    float s = 0.f, sq = 0.f;
#pragma unroll
    for (int it = 0; it < 8; ++it) {
      s += v[it].x + v[it].y + v[it].z + v[it].w;
      sq += v[it].x * v[it].x + v[it].y * v[it].y + v[it].z * v[it].z + v[it].w * v[it].w;
    }
    for (int d = 32; d; d >>= 1) { s += __shfl_xor(s, d, 64); sq += __shfl_xor(sq, d, 64); }
    float* red = smem;
    int wv = t >> 6, lane = t & 63;
    if (lane == 0) { red[wv] = s; red[4 + wv] = sq; }
    __syncthreads();
    if (t == 0) {
      atomicAdd(&stats[bg * 16], red[0] + red[1] + red[2] + red[3]);
      atomicAdd(&stats[256 + bg * 16], red[4] + red[5] + red[6] + red[7]);
    }
    return;
  }

  if (bid < 2432) {
    // ---- ln_kv, split into K-blocks and V-blocks ----
    int kb = bid - 2048;
    int doV = kb >= 192;
    if (doV) kb -= 192;
    int key = kb % 96;
    int b = kb / 96;
    size_t ko = (size_t)(b * 96 + key) * 256 + t;
    size_t vo = ((size_t)(b * 8 + (t >> 5)) * 32 + (t & 31)) * 96 + key;
    if (key >= 77) {
      if (doV) vh[vo] = 0; else kh[ko] = 0;
      return;
    }
    float* lnv = smem;
    float* red = smem + 768;
    const float* row = ctx + (size_t)(b * 77 + key) * 768;
    float v0 = row[t], v1 = row[t + 256], v2 = row[t + 512];
    float s = v0 + v1 + v2, sq = v0 * v0 + v1 * v1 + v2 * v2;
    for (int d = 32; d; d >>= 1) { s += __shfl_xor(s, d, 64); sq += __shfl_xor(sq, d, 64); }
    int wv = t >> 6, lane = t & 63;
    if (!lane) { red[wv] = s; red[4 + wv] = sq; }
    __syncthreads();
    float S = red[0] + red[1] + red[2] + red[3];
    float SQ = red[4] + red[5] + red[6] + red[7];
    const float invD = 1.0f / 768.0f;
    float mean = S * invD;
    float rstd = rsqrtf(SQ * invD - mean * mean + 1e-5f);
    lnv[t]       = (v0 - mean) * rstd * lng[t]       + lnb[t];
    lnv[t + 256] = (v1 - mean) * rstd * lng[t + 256] + lnb[t + 256];
    lnv[t + 512] = (v2 - mean) * rstd * lng[t + 512] + lnb[t + 512];
    __syncthreads();
    const float* W = doV ? Wv : Wk;
    float a0 = 0.f, a1 = 0.f, a2 = 0.f, a3 = 0.f;
    float a4 = 0.f, a5 = 0.f, a6 = 0.f, a7 = 0.f;
    for (int e = 0; e < 768; e += 8) {
      a0 += lnv[e] * W[(e) * 256 + t];         a1 += lnv[e + 1] * W[(e + 1) * 256 + t];
      a2 += lnv[e + 2] * W[(e + 2) * 256 + t]; a3 += lnv[e + 3] * W[(e + 3) * 256 + t];
      a4 += lnv[e + 4] * W[(e + 4) * 256 + t]; a5 += lnv[e + 5] * W[(e + 5) * 256 + t];
      a6 += lnv[e + 6] * W[(e + 6) * 256 + t]; a7 += lnv[e + 7] * W[(e + 7) * 256 + t];
    }
    float a = ((a0 + a1) + (a2 + a3)) + ((a4 + a5) + (a6 + a7));
    if (doV) vh[vo] = cvt16(a); else kh[ko] = cvt16(a);
    return;
  }

  // ---- prep_w: single fp16 plane ----
  {
    int pb = bid - 2432;
    int bx = pb & 15, by = (pb >> 4) & 15, bz = pb >> 8;
    float (*tile)[17] = (float(*)[17])smem;
    const float* src = bz ? wo : wq;
    u16* dst = bz ? wot : wqt;
    int r0 = by * 16, c0 = bx * 16;
    int r = t >> 4, c = t & 15;
    tile[r][c] = src[(r0 + r) * 256 + c0 + c];
    __syncthreads();
    dst[(c0 + r) * 256 + r0 + c] = cvt16(tile[c][r]);
  }
}

// ---------------- fused Q-proj + attention + out-proj ----------------
// grid 1024: b = blk>>9, s0 = (blk&511)*64. 256 threads = 4 waves.
// Round-8: SINGLE-PLANE WEIGHTS. Weight entries ~N(0,1/16): fp16 rounding
// contributes ~5e-4 to output, far below the 0.03 absmax band. Activations
// (x, attn_out) keep the hi/lo split. A/C inner loop: (ah+al)*bh = 2 MFMAs
// per acc (was 3); B-fragment loads halved. Per wave: MFMA 888->632,
// VMEM ~364->~236 -- the round-6/7-proven lever (issue volume).
__global__ __launch_bounds__(256, 2) void fused_qao(
    const float* __restrict__ x,
    const u16* __restrict__ wqt, const u16* __restrict__ wot,
    const u16* __restrict__ kws_hi, const u16* __restrict__ vtw_hi,
    const float* __restrict__ gng, const float* __restrict__ gnb,
    const float* __restrict__ stats,
    const float* __restrict__ bo, float* __restrict__ out) {
  __shared__ u16 qhi[64 * 256];  // GN(x)^T tile; then Q(hi); then attn_out
  __shared__ u16 qlo[64 * 256];  // GN lo; stale during attn; then attn_out lo
  int t = threadIdx.x, lane = t & 63, wv = t >> 6;
  int ml = lane & 15, quad = lane >> 4;
  int b = blockIdx.x >> 9;
  int s0 = (blockIdx.x & 511) * 64;

  // ---- Stage GN(x)^T tile [64 s][256 c] into qs (hi/lo), finalize GN inline.
  {
    const float invN = 1.0f / 1048576.0f;
    int sc_ = (t & 7) * 8;  // 8 consecutive s per thread
#pragma unroll
    for (int p = 0; p < 8; ++p) {
      int c = p * 32 + (t >> 3);
      int bg = b * 8 + (c >> 5);
      float mean = stats[bg * 16] * invN;
      float var = stats[256 + bg * 16] * invN - mean * mean;
      float rstd = rsqrtf(var + 1e-5f);
      float scale = rstd * gng[c];
      float shift = gnb[c] - mean * scale;
      size_t base = (((size_t)(b * 256 + c)) << 15) + s0 + sc_;
      float4 xv0 = *(const float4*)(x + base);
      float4 xv1 = *(const float4*)(x + base + 4);
      float xa[8] = {xv0.x, xv0.y, xv0.z, xv0.w, xv1.x, xv1.y, xv1.z, xv1.w};
#pragma unroll
      for (int e = 0; e < 8; ++e) {
        int o = qix(sc_ + e, c);
        splitf(xa[e] * scale + shift, &qhi[o], &qlo[o]);
      }
    }
  }
  __syncthreads();

  // ---- Step A: Q[64][256] = A-tile @ Wq^T. 4 row-blocks x 4 col-blocks/wave.
  floatx4 acc[4][4];
#pragma unroll
  for (int i = 0; i < 4; ++i)
#pragma unroll
    for (int j = 0; j < 4; ++j) acc[i][j] = (floatx4){0.f, 0.f, 0.f, 0.f};
  for (int k0 = 0; k0 < 256; k0 += 32) {
    half8 ah[4], al[4], bh[4];
#pragma unroll
    for (int j = 0; j < 4; ++j) {
      size_t wo_ = (size_t)(wv * 64 + j * 16 + ml) * 256 + k0 + quad * 8;
      bh[j] = *(const half8*)(wqt + wo_);
    }
#pragma unroll
    for (int i = 0; i < 4; ++i) {
      int idx = qix(i * 16 + ml, k0 + quad * 8);
      ah[i] = *(const half8*)&qhi[idx];
      al[i] = *(const half8*)&qlo[idx];
    }
#pragma unroll
    for (int i = 0; i < 4; ++i)
#pragma unroll
      for (int j = 0; j < 4; ++j) {
        acc[i][j] = __builtin_amdgcn_mfma_f32_16x16x32_f16(al[i], bh[j], acc[i][j], 0, 0, 0);
        acc[i][j] = __builtin_amdgcn_mfma_f32_16x16x32_f16(ah[i], bh[j], acc[i][j], 0, 0, 0);
      }
  }
  __syncthreads();  // all waves done reading A-tile before overwriting with Q
  // Q writeback: hi plane only (attention consumes fp16 Q; qlo is fully
  // overwritten by attn_out before Step C reads it).
#pragma unroll
  for (int i = 0; i < 4; ++i)
#pragma unroll
    for (int j = 0; j < 4; ++j)
#pragma unroll
      for (int r = 0; r < 4; ++r) {
        int o = qix(i * 16 + quad * 4 + r, wv * 64 + j * 16 + ml);
        qhi[o] = cvt16(acc[i][j][r]);
      }
  __syncthreads();  // Q complete (cross-wave columns)

  // ---- Step B: attention, in-register P, single-plane fp16 K/V/Q.
  int h0 = (wv >> 1) * 4;
  int r16 = (wv & 1) * 16;
  const float scl = 0.17677669529663687f;
  const floatx4 z = {0.f, 0.f, 0.f, 0.f};
  for (int hh = 0; hh < 4; ++hh) {
    int h = h0 + hh;
    half8 kbh[5];
#pragma unroll
    for (int kt = 0; kt < 5; ++kt) {
      size_t ko = (size_t)(b * 96 + kt * 16 + ml) * 256 + h * 32 + quad * 8;
      kbh[kt] = *(const half8*)(kws_hi + ko);
    }
    half4 vfh[2][5];
#pragma unroll
    for (int db = 0; db < 2; ++db)
#pragma unroll
      for (int kt = 0; kt < 5; ++kt) {
        size_t vo = (size_t)((b * 8 + h) * 32 + db * 16 + ml) * 96 + kt * 16 + quad * 4;
        vfh[db][kt] = *(const half4*)(vtw_hi + vo);
      }
#pragma unroll
    for (int rg = 0; rg < 2; ++rg) {
      int qrow = rg * 32 + r16 + ml;
      half8 qfh = *(const half8*)&qhi[qix(qrow, h * 32 + quad * 8)];
      // S^T = K x Q^T: lane holds S^T[key=kt*16+quad*4+r][q=qrow]
      floatx4 sc[5];
      __builtin_amdgcn_s_setprio(1);
#pragma unroll
      for (int kt = 0; kt < 5; ++kt)
        sc[kt] = __builtin_amdgcn_mfma_f32_16x16x32_f16(kbh[kt], qfh, z, 0, 0, 0);
      __builtin_amdgcn_s_setprio(0);
      // softmax over keys, per q: scalar + 2 shfl rounds across quads.
      float mx = -1e30f;
#pragma unroll
      for (int kt = 0; kt < 5; ++kt) {
        int kbase = kt * 16 + quad * 4;
#pragma unroll
        for (int r = 0; r < 4; ++r) {
          float v = (kbase + r < 77) ? sc[kt][r] * scl : -1e30f;
          sc[kt][r] = v;
          mx = fmaxf(mx, v);
        }
      }
      mx = fmaxf(mx, __shfl_xor(mx, 16, 64));
      mx = fmaxf(mx, __shfl_xor(mx, 32, 64));
      float sm = 0.f;
#pragma unroll
      for (int kt = 0; kt < 5; ++kt)
#pragma unroll
        for (int r = 0; r < 4; ++r) {
          float p = __expf(sc[kt][r] - mx);
          sc[kt][r] = p;
          sm += p;
        }
      sm += __shfl_xor(sm, 16, 64);
      sm += __shfl_xor(sm, 32, 64);
      float inv = 1.0f / sm;
      half4 pb[5];
#pragma unroll
      for (int kt = 0; kt < 5; ++kt) {
        pb[kt][0] = (_Float16)(sc[kt][0] * inv);
        pb[kt][1] = (_Float16)(sc[kt][1] * inv);
        pb[kt][2] = (_Float16)(sc[kt][2] * inv);
        pb[kt][3] = (_Float16)(sc[kt][3] * inv);
      }
      // PV^T via 16x16x16 MFMAs, P straight from registers.
      floatx4 o0 = z, o1 = z;
      __builtin_amdgcn_s_setprio(1);
#pragma unroll
      for (int kt = 0; kt < 5; ++kt) {
        o0 = __builtin_amdgcn_mfma_f32_16x16x16f16(vfh[0][kt], pb[kt], o0, 0, 0, 0);
        o1 = __builtin_amdgcn_mfma_f32_16x16x16f16(vfh[1][kt], pb[kt], o1, 0, 0, 0);
      }
      __builtin_amdgcn_s_setprio(0);
      // lane holds attn_out[q=qrow][d = db*16 + quad*4 + r] -> split write
      // (Step C consumes hi/lo).
#pragma unroll
      for (int r = 0; r < 4; ++r) {
        int o0i = qix(qrow, h * 32 + quad * 4 + r);
        splitf(o0[r], &qhi[o0i], &qlo[o0i]);
        int o1i = qix(qrow, h * 32 + 16 + quad * 4 + r);
        splitf(o1[r], &qhi[o1i], &qlo[o1i]);
      }
    }
  }
  __syncthreads();  // attn_out complete before Step C reads all columns

  // ---- Step C: out = attn_out @ Wo^T + bo + x.
#pragma unroll
  for (int i = 0; i < 4; ++i)
#pragma unroll
    for (int j = 0; j < 4; ++j) acc[i][j] = (floatx4){0.f, 0.f, 0.f, 0.f};
  for (int k0 = 0; k0 < 256; k0 += 32) {
    half8 ah[4], al[4], bh[4];
#pragma unroll
    for (int j = 0; j < 4; ++j) {
      size_t wo_ = (size_t)(wv * 64 + j * 16 + ml) * 256 + k0 + quad * 8;
      bh[j] = *(const half8*)(wot + wo_);
    }
#pragma unroll
    for (int i = 0; i < 4; ++i) {
      int idx = qix(i * 16 + ml, k0 + quad * 8);
      ah[i] = *(const half8*)&qhi[idx];
      al[i] = *(const half8*)&qlo[idx];
    }
#pragma unroll
    for (int i = 0; i < 4; ++i)
#pragma unroll
      for (int j = 0; j < 4; ++j) {
        acc[i][j] = __builtin_amdgcn_mfma_f32_16x16x32_f16(al[i], bh[j], acc[i][j], 0, 0, 0);
        acc[i][j] = __builtin_amdgcn_mfma_f32_16x16x32_f16(ah[i], bh[j], acc[i][j], 0, 0, 0);
      }
  }
#pragma unroll
  for (int i = 0; i < 4; ++i) {
    int sp = s0 + i * 16 + quad * 4;
#pragma unroll
    for (int j = 0; j < 4; ++j) {
      int col = wv * 64 + j * 16 + ml;
      float bias = bo[col];
      size_t o = (((size_t)(b * 256 + col)) << 15) + sp;
      float4 xv = *(const float4*)(x + o);
      float4 ov;
      ov.x = acc[i][j][0] + bias + xv.x;
      ov.y = acc[i][j][1] + bias + xv.y;
      ov.z = acc[i][j][2] + bias + xv.z;
      ov.w = acc[i][j][3] + bias + xv.w;
      *(float4*)(out + o) = ov;
    }
  }
}

extern "C" void kernel_launch(void* const* d_in, const int* in_sizes, int n_in,
                              void* d_out, int out_size, void* d_ws, size_t ws_size,
                              hipStream_t stream) {
  (void)out_size; (void)ws_size;
  int idx[11] = {0, 1, 2, 3, 4, 5, 6, 7, 8, 9, 10};  // x,ctx,gng,gnb,lng,lnb,Wq,Wk,Wv,Wo,bo
  static const int dsz[11] = {16777216, 118272, 256, 256, 768, 768,
                              65536, 196608, 196608, 65536, 256};
  bool dict = (n_in == 11);
  if (dict)
    for (int i = 0; i < 11; ++i)
      if (in_sizes[i] != dsz[i]) { dict = false; break; }
  if (!dict && n_in == 11) {
    static const int ssz[11] = {196608, 65536, 65536, 196608, 256, 118272,
                                256, 256, 768, 768, 16777216};
    bool srt = true;
    for (int i = 0; i < 11; ++i)
      if (in_sizes[i] != ssz[i]) { srt = false; break; }
    if (srt) {
      idx[0] = 10; idx[1] = 5; idx[2] = 7; idx[3] = 6; idx[4] = 9; idx[5] = 8;
      idx[6] = 2;  idx[7] = 0; idx[8] = 3; idx[9] = 1; idx[10] = 4;
    }
  }
  const float* x   = (const float*)d_in[idx[0]];
  const float* ctx = (const float*)d_in[idx[1]];
  const float* gng = (const float*)d_in[idx[2]];
  const float* gnb = (const float*)d_in[idx[3]];
  const float* lng = (const float*)d_in[idx[4]];
  const float* lnb = (const float*)d_in[idx[5]];
  const float* Wq  = (const float*)d_in[idx[6]];
  const float* Wk  = (const float*)d_in[idx[7]];
  const float* Wv  = (const float*)d_in[idx[8]];
  const float* Wo  = (const float*)d_in[idx[9]];
  const float* bo  = (const float*)d_in[idx[10]];
  float* out = (float*)d_out;

  u16* ws = (u16*)d_ws;
  float* stats = (float*)ws;  // 512 floats: gsum[g] at g*16, gsq[g] at 256+g*16
  u16* wqt    = ws + 1024;
  u16* wot    = wqt + 65536;
  u16* kws_hi = wot + 65536;
  u16* vtw_hi = kws_hi + 49152;

  hipMemsetAsync(stats, 0, 512 * sizeof(float), stream);
  prep_all<<<2944, 256, 0, stream>>>(x, stats, ctx, lng, lnb, Wk, Wv,
                                     kws_hi, vtw_hi,
                                     Wq, Wo, wqt, wot);
  fused_qao<<<1024, 256, 0, stream>>>(x, wqt, wot, kws_hi, vtw_hi,
                                      gng, gnb, stats, bo, out);
}